// Round 4
// baseline (201.206 us; speedup 1.0000x reference)
//
#include <hip/hip_runtime.h>
#include <hip/hip_bf16.h>

// Problem constants
#define B_    2
#define S_    2048
#define DIM_  512
#define H_    8
#define HD_   64
#define TOUT_ 1536   // 2*QK + DIM
#define ROWS_ (B_ * S_)   // 4096

typedef unsigned short ushort_t;
typedef __attribute__((ext_vector_type(8))) __bf16 bf16x8;
typedef __attribute__((ext_vector_type(4))) float floatx4;

#define AS_GLB __attribute__((address_space(1)))
#define AS_LDS __attribute__((address_space(3)))

// ---------- numeric helpers ----------
__device__ __forceinline__ unsigned short f2bfu(float f) {
    unsigned u = __float_as_uint(f);
    unsigned r = (u + 0x7fffu + ((u >> 16) & 1u)) >> 16;
    return (unsigned short)r;
}
__device__ __forceinline__ bf16x8 cvt8(const float* p) {
    float4 a = *reinterpret_cast<const float4*>(p);
    float4 b = *reinterpret_cast<const float4*>(p + 4);
    ushort_t o[8] = {f2bfu(a.x), f2bfu(a.y), f2bfu(a.z), f2bfu(a.w),
                     f2bfu(b.x), f2bfu(b.y), f2bfu(b.z), f2bfu(b.w)};
    return *reinterpret_cast<bf16x8*>(o);
}

// ---------- fused: mask classify+decode (last block) + fp32->bf16 casts ----------
#define XN4_  (ROWS_ * DIM_ / 4)                  // 524288
#define WTN4_ (TOUT_ * DIM_ / 4)                  // 196608
#define WON4_ (DIM_ * DIM_ / 4)                   // 65536
#define CASTBLKS_ ((XN4_ + WTN4_ + WON4_) / 256)  // 3072
__global__ __launch_bounds__(256) void prep_inputs(const float* __restrict__ x,
                                                   const float* __restrict__ wt,
                                                   const float* __restrict__ wo,
                                                   const unsigned char* __restrict__ mb,
                                                   ushort_t* __restrict__ xb,
                                                   ushort_t* __restrict__ wtb,
                                                   ushort_t* __restrict__ wob,
                                                   int* __restrict__ wm) {
    if (blockIdx.x >= CASTBLKS_) {
        // ---- mask classify + decode (single block) ----
        __shared__ int s_bf, s_f, s_u8;
        int tid = threadIdx.x;
        if (tid == 0) { s_bf = 0; s_f = 0; s_u8 = 0; }
        __syncthreads();
        int cbf = 0, cf = 0, cu8 = 0;
        for (int i = tid; i < 4096; i += 256) {
            unsigned char v = mb[i];
            if (v == 0x3F || v == 0x80) {
                cf++;
                if ((i & 3) == 1) cbf++;
            } else if (v != 0 && (i & 3) != 0) {
                cu8++;
            }
        }
        atomicAdd(&s_bf, cbf); atomicAdd(&s_f, cf); atomicAdd(&s_u8, cu8);
        __syncthreads();
        int cls = (s_bf > 0) ? 2 : (s_f > 0) ? 3 : (s_u8 > 0) ? 0 : 1;
        for (int i = tid; i < ROWS_; i += 256) {
            int v;
            if (cls == 0)      v = (mb[i] != 0);
            else if (cls == 1) v = (reinterpret_cast<const int*>(mb)[i] != 0);
            else if (cls == 2) v = ((reinterpret_cast<const unsigned short*>(mb)[i] & 0x7fffu) != 0);
            else               v = ((reinterpret_cast<const unsigned int*>(mb)[i] & 0x7fffffffu) != 0);
            wm[i] = v;
        }
        return;
    }
    int i = blockIdx.x * 256 + threadIdx.x;
    const float* s; ushort_t* d; int off;
    if (i < XN4_)              { s = x;  d = xb;  off = i; }
    else if (i < XN4_ + WTN4_) { s = wt; d = wtb; off = i - XN4_; }
    else                       { s = wo; d = wob; off = i - XN4_ - WTN4_; }
    float4 v = reinterpret_cast<const float4*>(s)[off];
    ushort_t o[4] = {f2bfu(v.x), f2bfu(v.y), f2bfu(v.z), f2bfu(v.w)};
    reinterpret_cast<uint2*>(d)[off] = *reinterpret_cast<uint2*>(o);
}

// ==================================================================
// MFMA GEMM (proven R5): C[M,N] = A[M,K] @ B[N,K]^T, XOR-swizzled LDS.
// OUT_BF16: epilogue casts to bf16 (used for gemm1 -> t).
// ==================================================================
template <int TM, int N, int K, bool OUT_BF16>
__global__ __launch_bounds__(256) void mfma_gemm_bt(const ushort_t* __restrict__ A,
                                                    const ushort_t* __restrict__ Bm,
                                                    void* __restrict__ Cout) {
    constexpr int FM = (TM + 31) / 32;
    __shared__ __align__(16) ushort_t As[TM * 64];
    __shared__ __align__(16) ushort_t Bs[128 * 64];
    int tid = threadIdx.x;
    int lane = tid & 63;
    int wv = tid >> 6;
    int wm = wv >> 1, wn = wv & 1;
    int quad = lane >> 4;
    int mrow = lane & 15;
    int bx = blockIdx.x;
    int by = blockIdx.y;

    floatx4 acc[FM][4];
#pragma unroll
    for (int i = 0; i < FM; i++)
#pragma unroll
        for (int j = 0; j < 4; j++) acc[i][j] = (floatx4){0.f, 0.f, 0.f, 0.f};

    for (int k0 = 0; k0 < K; k0 += 64) {
#pragma unroll
        for (int t = 0; t < TM / 32; t++) {
            int p = (wv * (TM / 32) + t) * 64 + lane;
            int row = p >> 3, cp = p & 7;
            int gc = cp ^ (row & 7);
            const ushort_t* ga = A + (size_t)(by * TM + row) * K + k0 + gc * 8;
            __builtin_amdgcn_global_load_lds((const AS_GLB unsigned int*)ga,
                                             (AS_LDS unsigned int*)&As[(size_t)(wv * (TM / 32) + t) * 64 * 8],
                                             16, 0, 0);
        }
#pragma unroll
        for (int t = 0; t < 4; t++) {
            int p = (wv * 4 + t) * 64 + lane;
            int row = p >> 3, cp = p & 7;
            int gc = cp ^ (row & 7);
            const ushort_t* gb = Bm + (size_t)(bx * 128 + row) * K + k0 + gc * 8;
            __builtin_amdgcn_global_load_lds((const AS_GLB unsigned int*)gb,
                                             (AS_LDS unsigned int*)&Bs[(size_t)(wv * 4 + t) * 64 * 8],
                                             16, 0, 0);
        }
        __syncthreads();
#pragma unroll
        for (int ks = 0; ks < 64; ks += 32) {
            int c = (ks >> 3) + quad;
            bf16x8 af[FM], bf[4];
#pragma unroll
            for (int i = 0; i < FM; i++) {
                int row = wm * (TM / 2) + i * 16 + mrow;
                int pos = row * 8 + (c ^ (row & 7));
                af[i] = *reinterpret_cast<const bf16x8*>(&As[pos * 8]);
            }
#pragma unroll
            for (int j = 0; j < 4; j++) {
                int row = wn * 64 + j * 16 + mrow;
                int pos = row * 8 + (c ^ (row & 7));
                bf[j] = *reinterpret_cast<const bf16x8*>(&Bs[pos * 8]);
            }
#pragma unroll
            for (int i = 0; i < FM; i++)
#pragma unroll
                for (int j = 0; j < 4; j++)
                    acc[i][j] = __builtin_amdgcn_mfma_f32_16x16x32_bf16(af[i], bf[j], acc[i][j], 0, 0, 0);
        }
        __syncthreads();
    }

    int col0 = bx * 128 + wn * 64 + mrow;
    int row0 = by * TM + wm * (TM / 2) + quad * 4;
    if constexpr (OUT_BF16) {
        ushort_t* C = reinterpret_cast<ushort_t*>(Cout);
#pragma unroll
        for (int i = 0; i < FM; i++)
#pragma unroll
            for (int j = 0; j < 4; j++)
#pragma unroll
                for (int r = 0; r < 4; r++)
                    C[(size_t)(row0 + i * 16 + r) * N + col0 + j * 16] = f2bfu(acc[i][j][r]);
    } else {
        float* C = reinterpret_cast<float*>(Cout);
#pragma unroll
        for (int i = 0; i < FM; i++)
#pragma unroll
            for (int j = 0; j < 4; j++)
#pragma unroll
                for (int r = 0; r < 4; r++)
                    C[(size_t)(row0 + i * 16 + r) * N + col0 + j * 16] = acc[i][j][r];
    }
}

// ==================================================================
// gemm2 with fused split-combine A-staging:
//   A[row][col] = (numer0+numer1)/(den0+den1) cast to bf16, staged
//   reg->LDS at the swizzled position (same mapping as load_lds path).
// TM=32, N=K=512. Replaces attn_combine + plain gemm2.
// ==================================================================
__global__ __launch_bounds__(256) void gemm2_fused(const float* __restrict__ numer,
                                                   const float* __restrict__ den,
                                                   const ushort_t* __restrict__ Bm,
                                                   float* __restrict__ C) {
    constexpr int TM = 32, N = DIM_, K = DIM_;
    __shared__ __align__(16) ushort_t As[TM * 64];
    __shared__ __align__(16) ushort_t Bs[128 * 64];
    int tid = threadIdx.x;
    int lane = tid & 63;
    int wv = tid >> 6;
    int wm = wv >> 1, wn = wv & 1;
    int quad = lane >> 4;
    int mrow = lane & 15;
    int bx = blockIdx.x;
    int by = blockIdx.y;

    floatx4 acc[4];
#pragma unroll
    for (int j = 0; j < 4; j++) acc[j] = (floatx4){0.f, 0.f, 0.f, 0.f};

    for (int k0 = 0; k0 < K; k0 += 64) {
        // ---- A-stage: fused combine (reg -> swizzled LDS) ----
        {
            int p = tid;                    // 0..255 = 32 rows x 8 col-chunks
            int row = p >> 3, cp = p & 7;
            int arow = by * TM + row;
            int col0 = k0 + cp * 8;
            int hh = col0 >> 6;
            float dsum = den[(size_t)arow * 8 + hh] + den[((size_t)ROWS_ + arow) * 8 + hh];
            float inv = 1.0f / dsum;
            const float* n0 = &numer[(size_t)arow * DIM_ + col0];
            const float* n1 = &numer[((size_t)ROWS_ + arow) * DIM_ + col0];
            float4 a0 = *reinterpret_cast<const float4*>(n0);
            float4 a1 = *reinterpret_cast<const float4*>(n0 + 4);
            float4 b0 = *reinterpret_cast<const float4*>(n1);
            float4 b1 = *reinterpret_cast<const float4*>(n1 + 4);
            ushort_t o[8] = {f2bfu((a0.x + b0.x) * inv), f2bfu((a0.y + b0.y) * inv),
                             f2bfu((a0.z + b0.z) * inv), f2bfu((a0.w + b0.w) * inv),
                             f2bfu((a1.x + b1.x) * inv), f2bfu((a1.y + b1.y) * inv),
                             f2bfu((a1.z + b1.z) * inv), f2bfu((a1.w + b1.w) * inv)};
            int pos = row * 8 + (cp ^ (row & 7));
            *reinterpret_cast<uint4*>(&As[pos * 8]) = *reinterpret_cast<const uint4*>(o);
        }
        // ---- B-stage via global_load_lds (unchanged) ----
#pragma unroll
        for (int t = 0; t < 4; t++) {
            int p = (wv * 4 + t) * 64 + lane;
            int row = p >> 3, cp = p & 7;
            int gc = cp ^ (row & 7);
            const ushort_t* gb = Bm + (size_t)(bx * 128 + row) * K + k0 + gc * 8;
            __builtin_amdgcn_global_load_lds((const AS_GLB unsigned int*)gb,
                                             (AS_LDS unsigned int*)&Bs[(size_t)(wv * 4 + t) * 64 * 8],
                                             16, 0, 0);
        }
        __syncthreads();
#pragma unroll
        for (int ks = 0; ks < 64; ks += 32) {
            int c = (ks >> 3) + quad;
            bf16x8 af, bf[4];
            {
                int row = wm * 16 + mrow;
                int pos = row * 8 + (c ^ (row & 7));
                af = *reinterpret_cast<const bf16x8*>(&As[pos * 8]);
            }
#pragma unroll
            for (int j = 0; j < 4; j++) {
                int row = wn * 64 + j * 16 + mrow;
                int pos = row * 8 + (c ^ (row & 7));
                bf[j] = *reinterpret_cast<const bf16x8*>(&Bs[pos * 8]);
            }
#pragma unroll
            for (int j = 0; j < 4; j++)
                acc[j] = __builtin_amdgcn_mfma_f32_16x16x32_bf16(af, bf[j], acc[j], 0, 0, 0);
        }
        __syncthreads();
    }

    int col0 = bx * 128 + wn * 64 + mrow;
    int row0 = by * TM + wm * 16 + quad * 4;
#pragma unroll
    for (int j = 0; j < 4; j++)
#pragma unroll
        for (int r = 0; r < 4; r++)
            C[(size_t)(row0 + r) * N + col0 + j * 16] = acc[j][r];
}

// ==================================================================
// MFMA rotation (proven R6, bf16 t input): per position s,
// out = in @ R_s^T if mask. One wave per s, no LDS, no barrier.
// K output is FRAGMENT-MAJOR: Kb[bh][kb][c][l][e].
// ==================================================================
__global__ __launch_bounds__(256) void rot_qk_mfma(const ushort_t* __restrict__ t,
                                                   const float* __restrict__ rotG,
                                                   const int* __restrict__ wm,
                                                   ushort_t* __restrict__ Qb,
                                                   ushort_t* __restrict__ Kb) {
    int lane = threadIdx.x & 63;
    int wv = threadIdx.x >> 6;
    int row = blockIdx.x * 4 + wv;     // b*2048 + s
    int b = row >> 11, s = row & 2047;
    int lm = lane & 15, quad = lane >> 4;
    const ushort_t* trow = t + (size_t)row * TOUT_;
    int kb = s >> 4, l = s & 15;

    if (wm[row]) {
        bf16x8 af[2];
#pragma unroll
        for (int kc = 0; kc < 2; kc++)
            af[kc] = *reinterpret_cast<const bf16x8*>(trow + lm * 64 + kc * 32 + quad * 8);

        const float* R = rotG + (size_t)row * 4096;
        floatx4 dacc[4];
#pragma unroll
        for (int nb = 0; nb < 4; nb++) dacc[nb] = (floatx4){0.f, 0.f, 0.f, 0.f};
#pragma unroll
        for (int nb = 0; nb < 4; nb++)
#pragma unroll
            for (int kc = 0; kc < 2; kc++) {
                bf16x8 bfr = cvt8(R + (size_t)(nb * 16 + lm) * 64 + kc * 32 + quad * 8);
                dacc[nb] = __builtin_amdgcn_mfma_f32_16x16x32_bf16(af[kc], bfr, dacc[nb], 0, 0, 0);
            }
#pragma unroll
        for (int nb = 0; nb < 4; nb++)
#pragma unroll
            for (int r = 0; r < 4; r++) {
                int vec = quad * 4 + r;
                int hh = vec & 7;
                ushort_t v = f2bfu(dacc[nb][r]);
                if (vec >= 8) {
                    int c = nb * 2 + (lm >> 3), e = lm & 7;
                    Kb[(((size_t)(b * 8 + hh) * 128 + kb) * 8 + c) * 128 + l * 8 + e] = v;
                } else {
                    Qb[((size_t)(b * 8 + hh) * 2048 + s) * 64 + nb * 16 + lm] = v;
                }
            }
    } else {
#pragma unroll
        for (int nb = 0; nb < 4; nb++)
#pragma unroll
            for (int r = 0; r < 4; r++) {
                int vec = quad * 4 + r;
                int hh = vec & 7;
                ushort_t v = trow[vec * 64 + nb * 16 + lm];
                if (vec >= 8) {
                    int c = nb * 2 + (lm >> 3), e = lm & 7;
                    Kb[(((size_t)(b * 8 + hh) * 128 + kb) * 8 + c) * 128 + l * 8 + e] = v;
                } else {
                    Qb[((size_t)(b * 8 + hh) * 2048 + s) * 64 + nb * 16 + lm] = v;
                }
            }
    }
}

// ---------- prep: V^T bf16 [bh][65][2048]; masked keys zeroed; row 64 = mask ----------
__global__ __launch_bounds__(256) void prep_vt(const ushort_t* __restrict__ t,
                                               const int* __restrict__ wm,
                                               ushort_t* __restrict__ VtG) {
    __shared__ ushort_t tile[64][72];
    __shared__ float mrow[64];
    int st = blockIdx.x;   // 0..31 (64-key tile)
    int bh = blockIdx.y;   // 0..15
    int b = bh >> 3, h = bh & 7;
    int tid = threadIdx.x;
    if (tid < 64) mrow[tid] = wm[b * 2048 + st * 64 + tid] ? 1.0f : 0.0f;
#pragma unroll
    for (int i = 0; i < 2; i++) {
        int q = i * 256 + tid;          // 0..511
        int r = q >> 3, c8 = (q & 7) * 8;
        uint4 v = *reinterpret_cast<const uint4*>(
            t + (size_t)(b * 2048 + st * 64 + r) * TOUT_ + 1024 + h * 64 + c8);
        *reinterpret_cast<uint4*>(&tile[r][c8]) = v;
    }
    __syncthreads();
#pragma unroll
    for (int i = 0; i < 8; i++) {
        int e = i * 256 + tid;          // 0..2047
        int d = e >> 5, sl = (e & 31) * 2;
        unsigned u0 = (mrow[sl]     != 0.f) ? (unsigned)tile[sl][d]     : 0u;
        unsigned u1 = (mrow[sl + 1] != 0.f) ? (unsigned)tile[sl + 1][d] : 0u;
        *reinterpret_cast<unsigned int*>(VtG + ((size_t)bh * 65 + d) * 2048 + st * 64 + sl) = u0 | (u1 << 16);
    }
    if (tid < 32) {
        int sl = tid * 2;
        unsigned m0 = mrow[sl]     != 0.f ? 0x3F80u : 0u;
        unsigned m1 = mrow[sl + 1] != 0.f ? 0x3F80u : 0u;
        *reinterpret_cast<unsigned int*>(VtG + ((size_t)bh * 65 + 64) * 2048 + st * 64 + sl) = m0 | (m1 << 16);
    }
}

// ==================================================================
// MFMA flash taylor-attention v7 = v6 + T3/T4 counted-vmcnt pipeline:
//  - raw s_barrier, NEVER vmcnt(0) in the main loop: per tile issue
//    order is pinned [mask(2) | stageV(2) | K(8)]; end-of-tile waits
//    vmcnt(8) (mask+stage retired, next-K stays in flight across the
//    barrier)
//  - static VsA/VsB double buffer (alias-analysis friendly)
//  - mask row in registers (uniform per-wave vmem counts, Vs = 64 rows)
//  - setprio(1) around both MFMA clusters
// Grid (32,8,4) = 1024 blocks = 4/CU co-resident, LDS 24.6 KB.
// ==================================================================
__global__ __launch_bounds__(256) void tmha_attn_mfma(const ushort_t* __restrict__ Qb,
                                                      const ushort_t* __restrict__ KbF,
                                                      const ushort_t* __restrict__ VtG,
                                                      float* __restrict__ numer,
                                                      float* __restrict__ den) {
    __shared__ __align__(16) ushort_t VsA[512 * 8];   // 8 KB
    __shared__ __align__(16) ushort_t VsB[512 * 8];   // 8 KB
    __shared__ __align__(16) ushort_t Ps[512 * 8];    // 8 KB
    int tid = threadIdx.x;
    int lane = tid & 63;
    int wv = tid >> 6;
    int lm = lane & 15;
    int quad = lane >> 4;
    int qt = blockIdx.x;       // 0..31
    int h = blockIdx.y;
    int z = blockIdx.z;
    int b = z >> 1;
    int ks = z & 1;
    int bh = b * 8 + h;

    const ushort_t* Kf   = KbF + (size_t)bh * 128 * 1024;   // [kb][c][l][e]
    const ushort_t* Vbh  = VtG + (size_t)bh * 65 * 2048;
    const ushort_t* Mrow = Vbh + (size_t)64 * 2048;         // mask row (global)

    bf16x8 qf[2];
    {
        const ushort_t* qp = Qb + ((size_t)bh * 2048 + qt * 64 + wv * 16 + lm) * 64 + quad * 8;
        qf[0] = *reinterpret_cast<const bf16x8*>(qp);
        qf[1] = *reinterpret_cast<const bf16x8*>(qp + 32);
    }

    bf16x8 vzero;
    *reinterpret_cast<uint4*>(&vzero) = (uint4){0u, 0u, 0u, 0u};

    floatx4 oacc[5];
#pragma unroll
    for (int j = 0; j < 5; j++) oacc[j] = (floatx4){0.f, 0.f, 0.f, 0.f};

    bf16x8 kr[4][2];
    auto loadK = [&](int kt) {
        int kb = kt >> 4;
#pragma unroll
        for (int j = 0; j < 4; j++)
#pragma unroll
            for (int kc = 0; kc < 2; kc++)
                kr[j][kc] = *reinterpret_cast<const bf16x8*>(
                    Kf + (((size_t)(kb + j) * 8 + kc * 4 + quad) * 16 + lm) * 8);
    };
    auto stageV = [&](ushort_t* Vw, int kt) {
#pragma unroll
        for (int t4 = 0; t4 < 2; t4++) {
            int p = (wv * 2 + t4) * 64 + lane;
            int row = p >> 3, cp = p & 7;
            int gc = cp ^ (row & 7);
            const ushort_t* g = Vbh + (size_t)row * 2048 + kt + gc * 8;
            __builtin_amdgcn_global_load_lds((const AS_GLB unsigned int*)g,
                                             (AS_LDS unsigned int*)&Vw[(wv * 2 + t4) * 64 * 8],
                                             16, 0, 0);
        }
    };

    auto tile = [&](const ushort_t* Vr, ushort_t* Vw, int kt, int ktn) {
        // vmem issue order (pinned): mask(2) | stageV(2) | loadK(8)
        bf16x8 mvb[2];
#pragma unroll
        for (int kc = 0; kc < 2; kc++)
            mvb[kc] = *reinterpret_cast<const bf16x8*>(Mrow + kt + (kc * 4 + quad) * 8);
        __builtin_amdgcn_sched_barrier(0);
        stageV(Vw, ktn);
        __builtin_amdgcn_sched_barrier(0);

        // ---- QK^T: operands entirely in registers ----
        floatx4 sacc[4];
#pragma unroll
        for (int j = 0; j < 4; j++) sacc[j] = (floatx4){0.f, 0.f, 0.f, 0.f};
        __builtin_amdgcn_s_setprio(1);
#pragma unroll
        for (int j = 0; j < 4; j++)
#pragma unroll
            for (int kc = 0; kc < 2; kc++)
                sacc[j] = __builtin_amdgcn_mfma_f32_16x16x32_bf16(qf[kc], kr[j][kc], sacc[j], 0, 0, 0);
        __builtin_amdgcn_s_setprio(0);

        loadK(ktn);                   // next K into kr (WAR on regs, in flight past the barrier)

        // ---- taylor weights -> P (bf16, swizzled, wave-private rows) ----
#pragma unroll
        for (int j = 0; j < 4; j++)
#pragma unroll
            for (int r = 0; r < 4; r++) {
                float s = sacc[j][r];
                float wgt = fmaf(s, fmaf(s, 0.0078125f, 0.125f), 1.0f);  // 1 + s/8 + s^2/128
                int m = wv * 16 + quad * 4 + r;
                int col = j * 16 + lm;
                int cw = col >> 3;
                int pos = m * 8 + (cw ^ (m & 7));
                Ps[pos * 8 + (col & 7)] = f2bfu(wgt);
            }
        asm volatile("s_waitcnt lgkmcnt(0)" ::: "memory");
        __builtin_amdgcn_sched_barrier(0);

        // ---- P @ V': O[16 q][64 dims] + denominator (mask frag in regs) ----
        int qrow_l = wv * 16 + lm;
        bf16x8 pa[2];
#pragma unroll
        for (int kc = 0; kc < 2; kc++) {
            int c = kc * 4 + quad;
            int ppos = qrow_l * 8 + (c ^ (qrow_l & 7));
            pa[kc] = *reinterpret_cast<const bf16x8*>(&Ps[ppos * 8]);
        }
        __builtin_amdgcn_s_setprio(1);
#pragma unroll
        for (int j = 0; j < 4; j++) {
            int vrow = j * 16 + lm;
#pragma unroll
            for (int kc = 0; kc < 2; kc++) {
                int c = kc * 4 + quad;
                int vpos = vrow * 8 + (c ^ (vrow & 7));
                bf16x8 vb = *reinterpret_cast<const bf16x8*>(&Vr[vpos * 8]);
                oacc[j] = __builtin_amdgcn_mfma_f32_16x16x32_bf16(pa[kc], vb, oacc[j], 0, 0, 0);
            }
        }
#pragma unroll
        for (int kc = 0; kc < 2; kc++) {
            bf16x8 vb = (lm == 0) ? mvb[kc] : vzero;   // denom row: n=0 carries mask
            oacc[4] = __builtin_amdgcn_mfma_f32_16x16x32_bf16(pa[kc], vb, oacc[4], 0, 0, 0);
        }
        __builtin_amdgcn_s_setprio(0);

        // ---- end of tile: own mask+stage retired, K loads stay in flight ----
        __builtin_amdgcn_sched_barrier(0);
        asm volatile("s_waitcnt vmcnt(8)" ::: "memory");
        __builtin_amdgcn_s_barrier();
    };

    int kt0 = ks * 1024;
    stageV(VsA, kt0);
    loadK(kt0);
    __syncthreads();   // prologue: full drain once
#pragma unroll 1
    for (int tt = 0; tt < 8; tt++) {
        int kt = kt0 + tt * 128;
        int kt1 = kt + 64;
        int kt2 = (tt == 7) ? kt0 : kt + 128;   // wrapped prefetch addr (values unused)
        tile(VsA, VsB, kt, kt1);
        tile(VsB, VsA, kt1, kt2);
    }

    // ---- epilogue: write split numerator + denominator (fp32) ----
#pragma unroll
    for (int j = 0; j < 4; j++)
#pragma unroll
        for (int r = 0; r < 4; r++) {
            int qrow = b * 2048 + qt * 64 + wv * 16 + quad * 4 + r;
            numer[((size_t)ks * ROWS_ + qrow) * DIM_ + h * 64 + j * 16 + lm] = oacc[j][r];
        }
    if (lm == 0) {
#pragma unroll
        for (int r = 0; r < 4; r++) {
            int qrow = b * 2048 + qt * 64 + wv * 16 + quad * 4 + r;
            den[((size_t)ks * ROWS_ + qrow) * 8 + h] = oacc[4][r];
        }
    }
}

extern "C" void kernel_launch(void* const* d_in, const int* in_sizes, int n_in,
                              void* d_out, int out_size, void* d_ws, size_t ws_size,
                              hipStream_t stream) {
    (void)in_sizes; (void)n_in; (void)out_size; (void)ws_size;
    const float* x    = (const float*)d_in[0];
    const void*  mask = d_in[1];
    const float* rot  = (const float*)d_in[2];
    const float* Wt   = (const float*)d_in[3];
    const float* Wo   = (const float*)d_in[4];

    char* ws = (char*)d_ws;
    int* wmask       = (int*)(ws + 64);                     // 16 KB
    ushort_t* t      = (ushort_t*)(ws + 32768);             // bf16 t: 12,582,912 B (region reserves 25 MB)
    ushort_t* Xb     = (ushort_t*)(ws + 25198592);          //  4,194,304 B
    ushort_t* Wtb    = (ushort_t*)(ws + 29392896);          //  1,572,864 B
    ushort_t* Wob    = (ushort_t*)(ws + 30965760);          //    524,288 B
    ushort_t* Qb     = (ushort_t*)(ws + 31490048);          //  4,194,304 B
    ushort_t* Kb     = (ushort_t*)(ws + 35684352);          //  4,194,304 B (fragment-major)
    ushort_t* VtG    = (ushort_t*)(ws + 39878656);          //  4,259,840 B
    // split-K attention outputs reuse t's region (t is dead after prep_vt)
    float* numer     = (float*)(ws + 32768);                // 2 * 4096 * 512 * 4 = 16,777,216 B
    float* den       = (float*)(ws + 32768 + 16777216);     // 2 * 4096 * 8 * 4 = 262,144 B

    // fused: mask classify+decode + bf16 casts (x, Wt, Wo)
    prep_inputs<<<CASTBLKS_ + 1, 256, 0, stream>>>(x, Wt, Wo, (const unsigned char*)mask,
                                                   Xb, Wtb, Wob, wmask);

    // gemm1: t = x @ Wt^T, bf16 output (TM=64 -> 768 blocks = 3/CU)
    {
        dim3 grid(TOUT_ / 128, ROWS_ / 64);
        mfma_gemm_bt<64, TOUT_, DIM_, true><<<grid, 256, 0, stream>>>(Xb, Wtb, (void*)t);
    }

    // MFMA rotation + q/k bf16 pack (1 wave per position, no LDS)
    rot_qk_mfma<<<ROWS_ / 4, 256, 0, stream>>>(t, rot, wmask, Qb, Kb);

    // masked V^T + mask-row prep
    {
        dim3 grid(32, 16);
        prep_vt<<<grid, 256, 0, stream>>>(t, wmask, VtG);
    }

    // MFMA flash taylor-attention, split-K (ksplit=2): 1024 blocks, 4/CU co-resident
    {
        dim3 grid(32, 8, 4);
        tmha_attn_mfma<<<grid, 256, 0, stream>>>(Qb, Kb, VtG, numer, den);
    }

    // gemm2 with fused combine: out = ((n0+n1)/(d0+d1)) @ Wo^T
    {
        dim3 grid(DIM_ / 128, ROWS_ / 32);
        gemm2_fused<<<grid, 256, 0, stream>>>(numer, den, Wob, (float*)d_out);
    }
}

// Round 5
// 197.731 us; speedup vs baseline: 1.0176x; 1.0176x over previous
//
#include <hip/hip_runtime.h>
#include <hip/hip_bf16.h>

// Problem constants
#define B_    2
#define S_    2048
#define DIM_  512
#define H_    8
#define HD_   64
#define TOUT_ 1536   // 2*QK + DIM
#define ROWS_ (B_ * S_)   // 4096

typedef unsigned short ushort_t;
typedef __attribute__((ext_vector_type(8))) __bf16 bf16x8;
typedef __attribute__((ext_vector_type(4))) float floatx4;

#define AS_GLB __attribute__((address_space(1)))
#define AS_LDS __attribute__((address_space(3)))

// ---------- numeric helpers ----------
__device__ __forceinline__ unsigned short f2bfu(float f) {
    unsigned u = __float_as_uint(f);
    unsigned r = (u + 0x7fffu + ((u >> 16) & 1u)) >> 16;
    return (unsigned short)r;
}
__device__ __forceinline__ bf16x8 cvt8(const float* p) {
    float4 a = *reinterpret_cast<const float4*>(p);
    float4 b = *reinterpret_cast<const float4*>(p + 4);
    ushort_t o[8] = {f2bfu(a.x), f2bfu(a.y), f2bfu(a.z), f2bfu(a.w),
                     f2bfu(b.x), f2bfu(b.y), f2bfu(b.z), f2bfu(b.w)};
    return *reinterpret_cast<bf16x8*>(o);
}

// ---------- fused: mask classify+decode (last block) + fp32->bf16 casts ----------
#define XN4_  (ROWS_ * DIM_ / 4)                  // 524288
#define WTN4_ (TOUT_ * DIM_ / 4)                  // 196608
#define WON4_ (DIM_ * DIM_ / 4)                   // 65536
#define CASTBLKS_ ((XN4_ + WTN4_ + WON4_) / 256)  // 3072
__global__ __launch_bounds__(256) void prep_inputs(const float* __restrict__ x,
                                                   const float* __restrict__ wt,
                                                   const float* __restrict__ wo,
                                                   const unsigned char* __restrict__ mb,
                                                   ushort_t* __restrict__ xb,
                                                   ushort_t* __restrict__ wtb,
                                                   ushort_t* __restrict__ wob,
                                                   int* __restrict__ wm) {
    if (blockIdx.x >= CASTBLKS_) {
        __shared__ int s_bf, s_f, s_u8;
        int tid = threadIdx.x;
        if (tid == 0) { s_bf = 0; s_f = 0; s_u8 = 0; }
        __syncthreads();
        int cbf = 0, cf = 0, cu8 = 0;
        for (int i = tid; i < 4096; i += 256) {
            unsigned char v = mb[i];
            if (v == 0x3F || v == 0x80) {
                cf++;
                if ((i & 3) == 1) cbf++;
            } else if (v != 0 && (i & 3) != 0) {
                cu8++;
            }
        }
        atomicAdd(&s_bf, cbf); atomicAdd(&s_f, cf); atomicAdd(&s_u8, cu8);
        __syncthreads();
        int cls = (s_bf > 0) ? 2 : (s_f > 0) ? 3 : (s_u8 > 0) ? 0 : 1;
        for (int i = tid; i < ROWS_; i += 256) {
            int v;
            if (cls == 0)      v = (mb[i] != 0);
            else if (cls == 1) v = (reinterpret_cast<const int*>(mb)[i] != 0);
            else if (cls == 2) v = ((reinterpret_cast<const unsigned short*>(mb)[i] & 0x7fffu) != 0);
            else               v = ((reinterpret_cast<const unsigned int*>(mb)[i] & 0x7fffffffu) != 0);
            wm[i] = v;
        }
        return;
    }
    int i = blockIdx.x * 256 + threadIdx.x;
    const float* s; ushort_t* d; int off;
    if (i < XN4_)              { s = x;  d = xb;  off = i; }
    else if (i < XN4_ + WTN4_) { s = wt; d = wtb; off = i - XN4_; }
    else                       { s = wo; d = wob; off = i - XN4_ - WTN4_; }
    float4 v = reinterpret_cast<const float4*>(s)[off];
    ushort_t o[4] = {f2bfu(v.x), f2bfu(v.y), f2bfu(v.z), f2bfu(v.w)};
    reinterpret_cast<uint2*>(d)[off] = *reinterpret_cast<uint2*>(o);
}

// ==================================================================
// MFMA GEMM (proven R5): C[M,N] = A[M,K] @ B[N,K]^T, XOR-swizzled LDS.
// OUT_BF16: epilogue casts to bf16 (used for gemm1 -> t).
// ==================================================================
template <int TM, int N, int K, bool OUT_BF16>
__global__ __launch_bounds__(256) void mfma_gemm_bt(const ushort_t* __restrict__ A,
                                                    const ushort_t* __restrict__ Bm,
                                                    void* __restrict__ Cout) {
    constexpr int FM = (TM + 31) / 32;
    __shared__ __align__(16) ushort_t As[TM * 64];
    __shared__ __align__(16) ushort_t Bs[128 * 64];
    int tid = threadIdx.x;
    int lane = tid & 63;
    int wv = tid >> 6;
    int wm = wv >> 1, wn = wv & 1;
    int quad = lane >> 4;
    int mrow = lane & 15;
    int bx = blockIdx.x;
    int by = blockIdx.y;

    floatx4 acc[FM][4];
#pragma unroll
    for (int i = 0; i < FM; i++)
#pragma unroll
        for (int j = 0; j < 4; j++) acc[i][j] = (floatx4){0.f, 0.f, 0.f, 0.f};

    for (int k0 = 0; k0 < K; k0 += 64) {
#pragma unroll
        for (int t = 0; t < TM / 32; t++) {
            int p = (wv * (TM / 32) + t) * 64 + lane;
            int row = p >> 3, cp = p & 7;
            int gc = cp ^ (row & 7);
            const ushort_t* ga = A + (size_t)(by * TM + row) * K + k0 + gc * 8;
            __builtin_amdgcn_global_load_lds((const AS_GLB unsigned int*)ga,
                                             (AS_LDS unsigned int*)&As[(size_t)(wv * (TM / 32) + t) * 64 * 8],
                                             16, 0, 0);
        }
#pragma unroll
        for (int t = 0; t < 4; t++) {
            int p = (wv * 4 + t) * 64 + lane;
            int row = p >> 3, cp = p & 7;
            int gc = cp ^ (row & 7);
            const ushort_t* gb = Bm + (size_t)(bx * 128 + row) * K + k0 + gc * 8;
            __builtin_amdgcn_global_load_lds((const AS_GLB unsigned int*)gb,
                                             (AS_LDS unsigned int*)&Bs[(size_t)(wv * 4 + t) * 64 * 8],
                                             16, 0, 0);
        }
        __syncthreads();
#pragma unroll
        for (int ks = 0; ks < 64; ks += 32) {
            int c = (ks >> 3) + quad;
            bf16x8 af[FM], bf[4];
#pragma unroll
            for (int i = 0; i < FM; i++) {
                int row = wm * (TM / 2) + i * 16 + mrow;
                int pos = row * 8 + (c ^ (row & 7));
                af[i] = *reinterpret_cast<const bf16x8*>(&As[pos * 8]);
            }
#pragma unroll
            for (int j = 0; j < 4; j++) {
                int row = wn * 64 + j * 16 + mrow;
                int pos = row * 8 + (c ^ (row & 7));
                bf[j] = *reinterpret_cast<const bf16x8*>(&Bs[pos * 8]);
            }
#pragma unroll
            for (int i = 0; i < FM; i++)
#pragma unroll
                for (int j = 0; j < 4; j++)
                    acc[i][j] = __builtin_amdgcn_mfma_f32_16x16x32_bf16(af[i], bf[j], acc[i][j], 0, 0, 0);
        }
        __syncthreads();
    }

    int col0 = bx * 128 + wn * 64 + mrow;
    int row0 = by * TM + wm * (TM / 2) + quad * 4;
    if constexpr (OUT_BF16) {
        ushort_t* C = reinterpret_cast<ushort_t*>(Cout);
#pragma unroll
        for (int i = 0; i < FM; i++)
#pragma unroll
            for (int j = 0; j < 4; j++)
#pragma unroll
                for (int r = 0; r < 4; r++)
                    C[(size_t)(row0 + i * 16 + r) * N + col0 + j * 16] = f2bfu(acc[i][j][r]);
    } else {
        float* C = reinterpret_cast<float*>(Cout);
#pragma unroll
        for (int i = 0; i < FM; i++)
#pragma unroll
            for (int j = 0; j < 4; j++)
#pragma unroll
                for (int r = 0; r < 4; r++)
                    C[(size_t)(row0 + i * 16 + r) * N + col0 + j * 16] = acc[i][j][r];
    }
}

// ==================================================================
// MFMA rotation (proven R6, bf16 t input): per position s,
// out = in @ R_s^T if mask. One wave per s, no LDS, no barrier.
// K output is FRAGMENT-MAJOR: Kb[bh][kb][c][l][e].
// ==================================================================
__global__ __launch_bounds__(256) void rot_qk_mfma(const ushort_t* __restrict__ t,
                                                   const float* __restrict__ rotG,
                                                   const int* __restrict__ wm,
                                                   ushort_t* __restrict__ Qb,
                                                   ushort_t* __restrict__ Kb) {
    int lane = threadIdx.x & 63;
    int wv = threadIdx.x >> 6;
    int row = blockIdx.x * 4 + wv;     // b*2048 + s
    int b = row >> 11, s = row & 2047;
    int lm = lane & 15, quad = lane >> 4;
    const ushort_t* trow = t + (size_t)row * TOUT_;
    int kb = s >> 4, l = s & 15;

    if (wm[row]) {
        bf16x8 af[2];
#pragma unroll
        for (int kc = 0; kc < 2; kc++)
            af[kc] = *reinterpret_cast<const bf16x8*>(trow + lm * 64 + kc * 32 + quad * 8);

        const float* R = rotG + (size_t)row * 4096;
        floatx4 dacc[4];
#pragma unroll
        for (int nb = 0; nb < 4; nb++) dacc[nb] = (floatx4){0.f, 0.f, 0.f, 0.f};
#pragma unroll
        for (int nb = 0; nb < 4; nb++)
#pragma unroll
            for (int kc = 0; kc < 2; kc++) {
                bf16x8 bfr = cvt8(R + (size_t)(nb * 16 + lm) * 64 + kc * 32 + quad * 8);
                dacc[nb] = __builtin_amdgcn_mfma_f32_16x16x32_bf16(af[kc], bfr, dacc[nb], 0, 0, 0);
            }
#pragma unroll
        for (int nb = 0; nb < 4; nb++)
#pragma unroll
            for (int r = 0; r < 4; r++) {
                int vec = quad * 4 + r;
                int hh = vec & 7;
                ushort_t v = f2bfu(dacc[nb][r]);
                if (vec >= 8) {
                    int c = nb * 2 + (lm >> 3), e = lm & 7;
                    Kb[(((size_t)(b * 8 + hh) * 128 + kb) * 8 + c) * 128 + l * 8 + e] = v;
                } else {
                    Qb[((size_t)(b * 8 + hh) * 2048 + s) * 64 + nb * 16 + lm] = v;
                }
            }
    } else {
#pragma unroll
        for (int nb = 0; nb < 4; nb++)
#pragma unroll
            for (int r = 0; r < 4; r++) {
                int vec = quad * 4 + r;
                int hh = vec & 7;
                ushort_t v = trow[vec * 64 + nb * 16 + lm];
                if (vec >= 8) {
                    int c = nb * 2 + (lm >> 3), e = lm & 7;
                    Kb[(((size_t)(b * 8 + hh) * 128 + kb) * 8 + c) * 128 + l * 8 + e] = v;
                } else {
                    Qb[((size_t)(b * 8 + hh) * 2048 + s) * 64 + nb * 16 + lm] = v;
                }
            }
    }
}

// ==================================================================
// prep: V^T FRAGMENT-MAJOR VtF[bh][st][chunk][d][e] (+ masked zeroing)
// and mask row MrowG[bh][2048] (bf16 1.0/0.0).
//   st = key-tile (64 keys), chunk = kc*4+quad (8 key-octets), d = dim,
//   e = key-within-octet. Attention's PV B-operand loads are then
//   1 KB-contiguous per wave instruction.
// ==================================================================
__global__ __launch_bounds__(256) void prep_vt(const ushort_t* __restrict__ t,
                                               const int* __restrict__ wm,
                                               ushort_t* __restrict__ VtF,
                                               ushort_t* __restrict__ MrowG) {
    __shared__ ushort_t tile[64][72];   // [key][dim]
    __shared__ ushort_t umask[64];
    int st = blockIdx.x;   // 0..31 (64-key tile)
    int bh = blockIdx.y;   // 0..15
    int b = bh >> 3, h = bh & 7;
    int tid = threadIdx.x;
    if (tid < 64) umask[tid] = wm[b * 2048 + st * 64 + tid] ? 0xFFFFu : 0u;
#pragma unroll
    for (int i = 0; i < 2; i++) {
        int q = i * 256 + tid;          // 0..511
        int r = q >> 3, c8 = (q & 7) * 8;
        uint4 v = *reinterpret_cast<const uint4*>(
            t + (size_t)(b * 2048 + st * 64 + r) * TOUT_ + 1024 + h * 64 + c8);
        *reinterpret_cast<uint4*>(&tile[r][c8]) = v;
    }
    __syncthreads();
    if (tid < 32) {
        int sl = tid * 2;
        unsigned m0 = umask[sl]     ? 0x3F80u : 0u;
        unsigned m1 = umask[sl + 1] ? 0x3F80u : 0u;
        *reinterpret_cast<unsigned int*>(MrowG + (size_t)bh * 2048 + st * 64 + sl) = m0 | (m1 << 16);
    }
#pragma unroll
    for (int it = 0; it < 2; it++) {
        int idx = tid + it * 256;       // 0..511
        int d = idx & 63;
        int chunk = idx >> 6;           // wave-uniform
        ushort_t o[8];
#pragma unroll
        for (int e = 0; e < 8; e++)
            o[e] = (ushort_t)(tile[chunk * 8 + e][d] & umask[chunk * 8 + e]);
        *reinterpret_cast<uint4*>(
            VtF + ((((size_t)bh * 32 + st) * 8 + chunk) * 64 + d) * 8) = *reinterpret_cast<const uint4*>(o);
    }
}

// ==================================================================
// MFMA flash taylor-attention v8: BARRIER-FREE.
//  - K, V, mask all fragment-major global -> registers (L1/L2-hot);
//    LDS carries only the wave-private P transpose (8 KB) -> zero
//    __syncthreads/s_barrier in the whole kernel; waves free-run with
//    per-register vmcnt tracking (no drain points).
//  - split-K removed: each block walks all 2048 keys and writes final
//    attnAb bf16 (denominator broadcast via __shfl from lm==0 lanes).
//  - prefetch chain: K[t+1] issued after QK(t); V/mask[t+1] after PV(t).
//  - XCD-bijective remap: 64 consecutive work items per XCD -> each
//    XCD L2 touches only 2 bh's K/V panels.
// Grid 512 blocks (2/CU exact), 256 thr, LDS 8 KB.
// ==================================================================
__global__ __launch_bounds__(256) void tmha_attn_mfma(const ushort_t* __restrict__ Qb,
                                                      const ushort_t* __restrict__ KbF,
                                                      const ushort_t* __restrict__ VtF,
                                                      const ushort_t* __restrict__ MrowG,
                                                      ushort_t* __restrict__ attnAb) {
    __shared__ __align__(16) ushort_t Ps[512 * 8];    // 8 KB, wave-private rows
    int tid = threadIdx.x;
    int lane = tid & 63;
    int wv = tid >> 6;
    int lm = lane & 15;
    int quad = lane >> 4;

    // XCD-bijective remap (512 = 8 XCDs x 64 contiguous works)
    int bid = blockIdx.x;
    int w = ((bid & 7) << 6) | (bid >> 3);
    int qt = w & 31;        // 0..31
    int bh = w >> 5;        // 0..15
    int b = bh >> 3, h = bh & 7;

    const ushort_t* Kf = KbF + (size_t)bh * 128 * 1024;        // [kb][c][l][e]
    const ushort_t* Vf = VtF + (size_t)bh * 32 * 8 * 64 * 8;   // [st][c][d][e]
    const ushort_t* Mr = MrowG + (size_t)bh * 2048;

    bf16x8 qf[2];
    {
        const ushort_t* qp = Qb + ((size_t)bh * 2048 + qt * 64 + wv * 16 + lm) * 64 + quad * 8;
        qf[0] = *reinterpret_cast<const bf16x8*>(qp);
        qf[1] = *reinterpret_cast<const bf16x8*>(qp + 32);
    }

    bf16x8 vzero;
    *reinterpret_cast<uint4*>(&vzero) = (uint4){0u, 0u, 0u, 0u};

    floatx4 oacc[5];
#pragma unroll
    for (int j = 0; j < 5; j++) oacc[j] = (floatx4){0.f, 0.f, 0.f, 0.f};

    bf16x8 kr[4][2], vr[4][2], mvb[2];
    auto loadK = [&](int kt) {
        int kb = kt >> 4;
#pragma unroll
        for (int j = 0; j < 4; j++)
#pragma unroll
            for (int kc = 0; kc < 2; kc++)
                kr[j][kc] = *reinterpret_cast<const bf16x8*>(
                    Kf + (((size_t)(kb + j) * 8 + kc * 4 + quad) * 16 + lm) * 8);
    };
    auto loadV = [&](int kt) {
        int st = kt >> 6;
#pragma unroll
        for (int j = 0; j < 4; j++)
#pragma unroll
            for (int kc = 0; kc < 2; kc++)
                vr[j][kc] = *reinterpret_cast<const bf16x8*>(
                    Vf + (((size_t)st * 8 + kc * 4 + quad) * 64 + j * 16 + lm) * 8);
    };
    auto loadM = [&](int kt) {
#pragma unroll
        for (int kc = 0; kc < 2; kc++)
            mvb[kc] = *reinterpret_cast<const bf16x8*>(Mr + kt + (kc * 4 + quad) * 8);
    };

    loadK(0); loadV(0); loadM(0);
#pragma unroll 1
    for (int tt = 0; tt < 32; tt++) {
        int kt = tt * 64;
        int ktn = (tt == 31) ? 0 : kt + 64;   // wrapped prefetch addr (values unused on last)

        // ---- QK^T: operands entirely in registers ----
        floatx4 sacc[4];
#pragma unroll
        for (int j = 0; j < 4; j++) sacc[j] = (floatx4){0.f, 0.f, 0.f, 0.f};
        __builtin_amdgcn_s_setprio(1);
#pragma unroll
        for (int j = 0; j < 4; j++)
#pragma unroll
            for (int kc = 0; kc < 2; kc++)
                sacc[j] = __builtin_amdgcn_mfma_f32_16x16x32_bf16(qf[kc], kr[j][kc], sacc[j], 0, 0, 0);
        __builtin_amdgcn_s_setprio(0);

        loadK(ktn);   // next K; in flight under P + PV

        // ---- taylor weights -> P (bf16, swizzled, wave-private rows) ----
#pragma unroll
        for (int j = 0; j < 4; j++)
#pragma unroll
            for (int r = 0; r < 4; r++) {
                float s = sacc[j][r];
                float wgt = fmaf(s, fmaf(s, 0.0078125f, 0.125f), 1.0f);  // 1 + s/8 + s^2/128
                int m = wv * 16 + quad * 4 + r;
                int col = j * 16 + lm;
                int cw = col >> 3;
                int pos = m * 8 + (cw ^ (m & 7));
                Ps[pos * 8 + (col & 7)] = f2bfu(wgt);
            }
        asm volatile("s_waitcnt lgkmcnt(0)" ::: "memory");
        __builtin_amdgcn_sched_barrier(0);

        // ---- P @ V': O[16 q][64 dims] + denominator ----
        int qrow_l = wv * 16 + lm;
        bf16x8 pa[2];
#pragma unroll
        for (int kc = 0; kc < 2; kc++) {
            int c = kc * 4 + quad;
            int ppos = qrow_l * 8 + (c ^ (qrow_l & 7));
            pa[kc] = *reinterpret_cast<const bf16x8*>(&Ps[ppos * 8]);
        }
        __builtin_amdgcn_s_setprio(1);
#pragma unroll
        for (int j = 0; j < 4; j++)
#pragma unroll
            for (int kc = 0; kc < 2; kc++)
                oacc[j] = __builtin_amdgcn_mfma_f32_16x16x32_bf16(pa[kc], vr[j][kc], oacc[j], 0, 0, 0);
#pragma unroll
        for (int kc = 0; kc < 2; kc++) {
            bf16x8 vb = (lm == 0) ? mvb[kc] : vzero;   // denom: col 0 carries mask row
            oacc[4] = __builtin_amdgcn_mfma_f32_16x16x32_bf16(pa[kc], vb, oacc[4], 0, 0, 0);
        }
        __builtin_amdgcn_s_setprio(0);

        loadV(ktn); loadM(ktn);   // next V/mask; in flight under next QK + P
    }

    // ---- epilogue: denominator broadcast + divide + bf16 write ----
    float inv[4];
#pragma unroll
    for (int r = 0; r < 4; r++) {
        float dn = __shfl(oacc[4][r], lane & 48);   // from lm==0 lane of this quad
        inv[r] = 1.0f / dn;
    }
#pragma unroll
    for (int j = 0; j < 4; j++)
#pragma unroll
        for (int r = 0; r < 4; r++) {
            int qrow = b * 2048 + qt * 64 + wv * 16 + quad * 4 + r;
            attnAb[(size_t)qrow * DIM_ + h * 64 + j * 16 + lm] = f2bfu(oacc[j][r] * inv[r]);
        }
}

extern "C" void kernel_launch(void* const* d_in, const int* in_sizes, int n_in,
                              void* d_out, int out_size, void* d_ws, size_t ws_size,
                              hipStream_t stream) {
    (void)in_sizes; (void)n_in; (void)out_size; (void)ws_size;
    const float* x    = (const float*)d_in[0];
    const void*  mask = d_in[1];
    const float* rot  = (const float*)d_in[2];
    const float* Wt   = (const float*)d_in[3];
    const float* Wo   = (const float*)d_in[4];

    char* ws = (char*)d_ws;
    int* wmask       = (int*)(ws + 64);                     // 16 KB
    ushort_t* t      = (ushort_t*)(ws + 32768);             // bf16 t: 12,582,912 B
    ushort_t* Xb     = (ushort_t*)(ws + 25198592);          //  4,194,304 B
    ushort_t* Wtb    = (ushort_t*)(ws + 29392896);          //  1,572,864 B
    ushort_t* Wob    = (ushort_t*)(ws + 30965760);          //    524,288 B
    ushort_t* Qb     = (ushort_t*)(ws + 31490048);          //  4,194,304 B
    ushort_t* Kb     = (ushort_t*)(ws + 35684352);          //  4,194,304 B (fragment-major)
    ushort_t* VtF    = (ushort_t*)(ws + 39878656);          //  4,194,304 B (fragment-major)
    ushort_t* MrowG  = (ushort_t*)(ws + 44072960);          //     65,536 B
    ushort_t* attnAb = (ushort_t*)(ws + 44138496);          //  4,194,304 B -> ends 48,332,800

    // fused: mask classify+decode + bf16 casts (x, Wt, Wo)
    prep_inputs<<<CASTBLKS_ + 1, 256, 0, stream>>>(x, Wt, Wo, (const unsigned char*)mask,
                                                   Xb, Wtb, Wob, wmask);

    // gemm1: t = x @ Wt^T, bf16 output (TM=64 -> 768 blocks = 3/CU)
    {
        dim3 grid(TOUT_ / 128, ROWS_ / 64);
        mfma_gemm_bt<64, TOUT_, DIM_, true><<<grid, 256, 0, stream>>>(Xb, Wtb, (void*)t);
    }

    // MFMA rotation + q/k bf16 pack (1 wave per position, no LDS)
    rot_qk_mfma<<<ROWS_ / 4, 256, 0, stream>>>(t, rot, wmask, Qb, Kb);

    // masked V^T fragment-major + mask row
    {
        dim3 grid(32, 16);
        prep_vt<<<grid, 256, 0, stream>>>(t, wmask, VtF, MrowG);
    }

    // MFMA flash taylor-attention v8: barrier-free, 512 blocks = 2/CU exact
    tmha_attn_mfma<<<512, 256, 0, stream>>>(Qb, Kb, VtF, MrowG, attnAb);

    // gemm2: out = attn @ Wo^T  (TM=32 -> 512 blocks = 2/CU)
    {
        dim3 grid(DIM_ / 128, ROWS_ / 32);
        mfma_gemm_bt<32, DIM_, DIM_, false><<<grid, 256, 0, stream>>>(attnAb, Wob, d_out);
    }
}

// Round 7
// 195.223 us; speedup vs baseline: 1.0306x; 1.0128x over previous
//
#include <hip/hip_runtime.h>
#include <hip/hip_bf16.h>

// Problem constants
#define B_    2
#define S_    2048
#define DIM_  512
#define H_    8
#define HD_   64
#define TOUT_ 1536   // 2*QK + DIM
#define ROWS_ (B_ * S_)   // 4096

typedef unsigned short ushort_t;
typedef __attribute__((ext_vector_type(8))) __bf16 bf16x8;
typedef __attribute__((ext_vector_type(4))) float floatx4;

#define AS_GLB __attribute__((address_space(1)))
#define AS_LDS __attribute__((address_space(3)))

// ---------- numeric helpers ----------
__device__ __forceinline__ unsigned short f2bfu(float f) {
    unsigned u = __float_as_uint(f);
    unsigned r = (u + 0x7fffu + ((u >> 16) & 1u)) >> 16;
    return (unsigned short)r;
}
__device__ __forceinline__ bf16x8 cvt8(const float* p) {
    float4 a = *reinterpret_cast<const float4*>(p);
    float4 b = *reinterpret_cast<const float4*>(p + 4);
    ushort_t o[8] = {f2bfu(a.x), f2bfu(a.y), f2bfu(a.z), f2bfu(a.w),
                     f2bfu(b.x), f2bfu(b.y), f2bfu(b.z), f2bfu(b.w)};
    return *reinterpret_cast<bf16x8*>(o);
}

// ---------- fused: mask classify+decode (last block) + fp32->bf16 casts ----------
#define XN4_  (ROWS_ * DIM_ / 4)                  // 524288
#define WTN4_ (TOUT_ * DIM_ / 4)                  // 196608
#define WON4_ (DIM_ * DIM_ / 4)                   // 65536
#define CASTBLKS_ ((XN4_ + WTN4_ + WON4_) / 256)  // 3072
__global__ __launch_bounds__(256) void prep_inputs(const float* __restrict__ x,
                                                   const float* __restrict__ wt,
                                                   const float* __restrict__ wo,
                                                   const unsigned char* __restrict__ mb,
                                                   ushort_t* __restrict__ xb,
                                                   ushort_t* __restrict__ wtb,
                                                   ushort_t* __restrict__ wob,
                                                   int* __restrict__ wm) {
    if (blockIdx.x >= CASTBLKS_) {
        __shared__ int s_bf, s_f, s_u8;
        int tid = threadIdx.x;
        if (tid == 0) { s_bf = 0; s_f = 0; s_u8 = 0; }
        __syncthreads();
        int cbf = 0, cf = 0, cu8 = 0;
        for (int i = tid; i < 4096; i += 256) {
            unsigned char v = mb[i];
            if (v == 0x3F || v == 0x80) {
                cf++;
                if ((i & 3) == 1) cbf++;
            } else if (v != 0 && (i & 3) != 0) {
                cu8++;
            }
        }
        atomicAdd(&s_bf, cbf); atomicAdd(&s_f, cf); atomicAdd(&s_u8, cu8);
        __syncthreads();
        int cls = (s_bf > 0) ? 2 : (s_f > 0) ? 3 : (s_u8 > 0) ? 0 : 1;
        for (int i = tid; i < ROWS_; i += 256) {
            int v;
            if (cls == 0)      v = (mb[i] != 0);
            else if (cls == 1) v = (reinterpret_cast<const int*>(mb)[i] != 0);
            else if (cls == 2) v = ((reinterpret_cast<const unsigned short*>(mb)[i] & 0x7fffu) != 0);
            else               v = ((reinterpret_cast<const unsigned int*>(mb)[i] & 0x7fffffffu) != 0);
            wm[i] = v;
        }
        return;
    }
    int i = blockIdx.x * 256 + threadIdx.x;
    const float* s; ushort_t* d; int off;
    if (i < XN4_)              { s = x;  d = xb;  off = i; }
    else if (i < XN4_ + WTN4_) { s = wt; d = wtb; off = i - XN4_; }
    else                       { s = wo; d = wob; off = i - XN4_ - WTN4_; }
    float4 v = reinterpret_cast<const float4*>(s)[off];
    ushort_t o[4] = {f2bfu(v.x), f2bfu(v.y), f2bfu(v.z), f2bfu(v.w)};
    reinterpret_cast<uint2*>(d)[off] = *reinterpret_cast<uint2*>(o);
}

// ==================================================================
// MFMA GEMM (proven R5): C[M,N] = A[M,K] @ B[N,K]^T, XOR-swizzled LDS.
// ==================================================================
template <int TM, int N, int K, bool OUT_BF16>
__global__ __launch_bounds__(256) void mfma_gemm_bt(const ushort_t* __restrict__ A,
                                                    const ushort_t* __restrict__ Bm,
                                                    void* __restrict__ Cout) {
    constexpr int FM = (TM + 31) / 32;
    __shared__ __align__(16) ushort_t As[TM * 64];
    __shared__ __align__(16) ushort_t Bs[128 * 64];
    int tid = threadIdx.x;
    int lane = tid & 63;
    int wv = tid >> 6;
    int wm = wv >> 1, wn = wv & 1;
    int quad = lane >> 4;
    int mrow = lane & 15;
    int bx = blockIdx.x;
    int by = blockIdx.y;

    floatx4 acc[FM][4];
#pragma unroll
    for (int i = 0; i < FM; i++)
#pragma unroll
        for (int j = 0; j < 4; j++) acc[i][j] = (floatx4){0.f, 0.f, 0.f, 0.f};

    for (int k0 = 0; k0 < K; k0 += 64) {
#pragma unroll
        for (int t = 0; t < TM / 32; t++) {
            int p = (wv * (TM / 32) + t) * 64 + lane;
            int row = p >> 3, cp = p & 7;
            int gc = cp ^ (row & 7);
            const ushort_t* ga = A + (size_t)(by * TM + row) * K + k0 + gc * 8;
            __builtin_amdgcn_global_load_lds((const AS_GLB unsigned int*)ga,
                                             (AS_LDS unsigned int*)&As[(size_t)(wv * (TM / 32) + t) * 64 * 8],
                                             16, 0, 0);
        }
#pragma unroll
        for (int t = 0; t < 4; t++) {
            int p = (wv * 4 + t) * 64 + lane;
            int row = p >> 3, cp = p & 7;
            int gc = cp ^ (row & 7);
            const ushort_t* gb = Bm + (size_t)(bx * 128 + row) * K + k0 + gc * 8;
            __builtin_amdgcn_global_load_lds((const AS_GLB unsigned int*)gb,
                                             (AS_LDS unsigned int*)&Bs[(size_t)(wv * 4 + t) * 64 * 8],
                                             16, 0, 0);
        }
        __syncthreads();
#pragma unroll
        for (int ks = 0; ks < 64; ks += 32) {
            int c = (ks >> 3) + quad;
            bf16x8 af[FM], bf[4];
#pragma unroll
            for (int i = 0; i < FM; i++) {
                int row = wm * (TM / 2) + i * 16 + mrow;
                int pos = row * 8 + (c ^ (row & 7));
                af[i] = *reinterpret_cast<const bf16x8*>(&As[pos * 8]);
            }
#pragma unroll
            for (int j = 0; j < 4; j++) {
                int row = wn * 64 + j * 16 + mrow;
                int pos = row * 8 + (c ^ (row & 7));
                bf[j] = *reinterpret_cast<const bf16x8*>(&Bs[pos * 8]);
            }
#pragma unroll
            for (int i = 0; i < FM; i++)
#pragma unroll
                for (int j = 0; j < 4; j++)
                    acc[i][j] = __builtin_amdgcn_mfma_f32_16x16x32_bf16(af[i], bf[j], acc[i][j], 0, 0, 0);
        }
        __syncthreads();
    }

    int col0 = bx * 128 + wn * 64 + mrow;
    int row0 = by * TM + wm * (TM / 2) + quad * 4;
    if constexpr (OUT_BF16) {
        ushort_t* C = reinterpret_cast<ushort_t*>(Cout);
#pragma unroll
        for (int i = 0; i < FM; i++)
#pragma unroll
            for (int j = 0; j < 4; j++)
#pragma unroll
                for (int r = 0; r < 4; r++)
                    C[(size_t)(row0 + i * 16 + r) * N + col0 + j * 16] = f2bfu(acc[i][j][r]);
    } else {
        float* C = reinterpret_cast<float*>(Cout);
#pragma unroll
        for (int i = 0; i < FM; i++)
#pragma unroll
            for (int j = 0; j < 4; j++)
#pragma unroll
                for (int r = 0; r < 4; r++)
                    C[(size_t)(row0 + i * 16 + r) * N + col0 + j * 16] = acc[i][j][r];
    }
}

// ==================================================================
// MFMA rotation (proven R6, bf16 t input): per position s,
// out = in @ R_s^T if mask. One wave per s, no LDS, no barrier.
// K output is FRAGMENT-MAJOR: Kb[bh][kb][c][l][e].
// ==================================================================
__global__ __launch_bounds__(256) void rot_qk_mfma(const ushort_t* __restrict__ t,
                                                   const float* __restrict__ rotG,
                                                   const int* __restrict__ wm,
                                                   ushort_t* __restrict__ Qb,
                                                   ushort_t* __restrict__ Kb) {
    int lane = threadIdx.x & 63;
    int wv = threadIdx.x >> 6;
    int row = blockIdx.x * 4 + wv;     // b*2048 + s
    int b = row >> 11, s = row & 2047;
    int lm = lane & 15, quad = lane >> 4;
    const ushort_t* trow = t + (size_t)row * TOUT_;
    int kb = s >> 4, l = s & 15;

    if (wm[row]) {
        bf16x8 af[2];
#pragma unroll
        for (int kc = 0; kc < 2; kc++)
            af[kc] = *reinterpret_cast<const bf16x8*>(trow + lm * 64 + kc * 32 + quad * 8);

        const float* R = rotG + (size_t)row * 4096;
        floatx4 dacc[4];
#pragma unroll
        for (int nb = 0; nb < 4; nb++) dacc[nb] = (floatx4){0.f, 0.f, 0.f, 0.f};
#pragma unroll
        for (int nb = 0; nb < 4; nb++)
#pragma unroll
            for (int kc = 0; kc < 2; kc++) {
                bf16x8 bfr = cvt8(R + (size_t)(nb * 16 + lm) * 64 + kc * 32 + quad * 8);
                dacc[nb] = __builtin_amdgcn_mfma_f32_16x16x32_bf16(af[kc], bfr, dacc[nb], 0, 0, 0);
            }
#pragma unroll
        for (int nb = 0; nb < 4; nb++)
#pragma unroll
            for (int r = 0; r < 4; r++) {
                int vec = quad * 4 + r;
                int hh = vec & 7;
                ushort_t v = f2bfu(dacc[nb][r]);
                if (vec >= 8) {
                    int c = nb * 2 + (lm >> 3), e = lm & 7;
                    Kb[(((size_t)(b * 8 + hh) * 128 + kb) * 8 + c) * 128 + l * 8 + e] = v;
                } else {
                    Qb[((size_t)(b * 8 + hh) * 2048 + s) * 64 + nb * 16 + lm] = v;
                }
            }
    } else {
#pragma unroll
        for (int nb = 0; nb < 4; nb++)
#pragma unroll
            for (int r = 0; r < 4; r++) {
                int vec = quad * 4 + r;
                int hh = vec & 7;
                ushort_t v = trow[vec * 64 + nb * 16 + lm];
                if (vec >= 8) {
                    int c = nb * 2 + (lm >> 3), e = lm & 7;
                    Kb[(((size_t)(b * 8 + hh) * 128 + kb) * 8 + c) * 128 + l * 8 + e] = v;
                } else {
                    Qb[((size_t)(b * 8 + hh) * 2048 + s) * 64 + nb * 16 + lm] = v;
                }
            }
    }
}

// ==================================================================
// prep: V in PV-B-fragment order for 16x16x32 MFMA, masked.
// Layout: VtF[((((bh*32+st)*5+dn)*2+jj)*4+quad)*16+lm]*8 + e
//   key(jj,quad,e) = jj*32 + (e>>2)*16 + quad*4 + (e&3)   (global: st*64+..)
//   value(dn<4) = V[key][d=dn*16+lm] * mask[key]
//   value(dn=4) = (lm==0) ? mask[key] : 0      (denominator block)
// ==================================================================
__global__ __launch_bounds__(256) void prep_vt(const ushort_t* __restrict__ t,
                                               const int* __restrict__ wm,
                                               ushort_t* __restrict__ VtF) {
    __shared__ ushort_t tile[64][72];   // [key][dim]
    __shared__ ushort_t umask[64];
    int st = blockIdx.x;   // 0..31 (64-key tile)
    int bh = blockIdx.y;   // 0..15
    int b = bh >> 3, h = bh & 7;
    int tid = threadIdx.x;
    if (tid < 64) umask[tid] = wm[b * 2048 + st * 64 + tid] ? 0xFFFFu : 0u;
#pragma unroll
    for (int i = 0; i < 2; i++) {
        int q = i * 256 + tid;          // 0..511
        int r = q >> 3, c8 = (q & 7) * 8;
        uint4 v = *reinterpret_cast<const uint4*>(
            t + (size_t)(b * 2048 + st * 64 + r) * TOUT_ + 1024 + h * 64 + c8);
        *reinterpret_cast<uint4*>(&tile[r][c8]) = v;
    }
    __syncthreads();
    {   // dn = 0..3 : one thread per (dn, quad, lm); writes jj=0,1
        int dn = tid >> 6, quad = (tid >> 4) & 3, lm = tid & 15;
#pragma unroll
        for (int jj = 0; jj < 2; jj++) {
            ushort_t o[8];
#pragma unroll
            for (int e = 0; e < 8; e++) {
                int key = jj * 32 + ((e >> 2) << 4) + quad * 4 + (e & 3);
                o[e] = (ushort_t)(tile[key][dn * 16 + lm] & umask[key]);
            }
            size_t base = (((((size_t)(bh * 32 + st) * 5 + dn) * 2 + jj) * 4 + quad) * 16 + lm) * 8;
            *reinterpret_cast<uint4*>(VtF + base) = *reinterpret_cast<const uint4*>(o);
        }
    }
    if (tid < 64) {   // dn = 4 : denominator/mask block
        int quad = tid >> 4, lm = tid & 15;
#pragma unroll
        for (int jj = 0; jj < 2; jj++) {
            ushort_t o[8];
#pragma unroll
            for (int e = 0; e < 8; e++) {
                int key = jj * 32 + ((e >> 2) << 4) + quad * 4 + (e & 3);
                o[e] = (lm == 0) ? (umask[key] ? (ushort_t)0x3F80u : (ushort_t)0u) : (ushort_t)0u;
            }
            size_t base = (((((size_t)(bh * 32 + st) * 5 + 4) * 2 + jj) * 4 + quad) * 16 + lm) * 8;
            *reinterpret_cast<uint4*>(VtF + base) = *reinterpret_cast<const uint4*>(o);
        }
    }
}

// ==================================================================
// MFMA flash taylor-attention v10: LDS-free, barrier-free, P-in-register,
// INTRINSICS ONLY (v9's inline-asm hazard bug fixed by construction).
//  - swapped QK^T (mfma(K,Q)): sacc[j][r] = S[key=j*16+quad*4+r][q=lm]
//  - P packed as A-fragment of 16x16x32: pa8[jj] = [sacc[2jj][0..3],
//    sacc[2jj+1][0..3]]; V precomputed in the matching B-fragment
//    permutation key(jj,quad,e) = jj*32+(e>>2)*16+quad*4+(e&3)
//  - PV + denominator = 10 intrinsic MFMAs; compiler handles all
//    hazards/waitcnts. Zero LDS, zero barriers, zero inline asm.
// Grid 512 blocks (2/CU), 256 thr.
// ==================================================================
__global__ __launch_bounds__(256) void tmha_attn_mfma(const ushort_t* __restrict__ Qb,
                                                      const ushort_t* __restrict__ KbF,
                                                      const ushort_t* __restrict__ VtF,
                                                      ushort_t* __restrict__ attnAb) {
    int tid = threadIdx.x;
    int lane = tid & 63;
    int wv = tid >> 6;
    int lm = lane & 15;
    int quad = lane >> 4;

    // XCD-bijective remap (512 = 8 XCDs x 64 contiguous works)
    int bid = blockIdx.x;
    int w = ((bid & 7) << 6) | (bid >> 3);
    int qt = w & 31;        // 0..31
    int bh = w >> 5;        // 0..15
    int b = bh >> 3, h = bh & 7;

    const ushort_t* Kf = KbF + (size_t)bh * 128 * 1024;       // [kb][c][l][e]
    const ushort_t* Vf = VtF + (size_t)bh * 163840;           // [st][dn][jj][quad][lm][e]

    bf16x8 qf[2];
    {
        const ushort_t* qp = Qb + ((size_t)bh * 2048 + qt * 64 + wv * 16 + lm) * 64 + quad * 8;
        qf[0] = *reinterpret_cast<const bf16x8*>(qp);
        qf[1] = *reinterpret_cast<const bf16x8*>(qp + 32);
    }

    floatx4 zero4 = (floatx4){0.f, 0.f, 0.f, 0.f};
    floatx4 oacc[5];
#pragma unroll
    for (int j = 0; j < 5; j++) oacc[j] = zero4;

    bf16x8 kr[4][2];
    bf16x8 vr[5][2];
    auto loadK = [&](int kt) {
        int kb = kt >> 4;
#pragma unroll
        for (int j = 0; j < 4; j++)
#pragma unroll
            for (int kc = 0; kc < 2; kc++)
                kr[j][kc] = *reinterpret_cast<const bf16x8*>(
                    Kf + (((size_t)(kb + j) * 8 + kc * 4 + quad) * 16 + lm) * 8);
    };
    auto loadV = [&](int kt) {
        const ushort_t* p = Vf + (size_t)(kt >> 6) * 5120 + quad * 128 + lm * 8;
#pragma unroll
        for (int dn = 0; dn < 5; dn++)
#pragma unroll
            for (int jj = 0; jj < 2; jj++)
                vr[dn][jj] = *reinterpret_cast<const bf16x8*>(p + dn * 1024 + jj * 512);
    };

    loadK(0); loadV(0);
#pragma unroll 1
    for (int tt = 0; tt < 32; tt++) {
        int ktn = (tt == 31) ? 0 : (tt + 1) * 64;   // wrapped prefetch addr (values unused on last)

        // ---- swapped QK^T: sacc[j][r] = S[key=j*16+quad*4+r][q=lm] ----
        floatx4 sacc[4];
        __builtin_amdgcn_s_setprio(1);
#pragma unroll
        for (int j = 0; j < 4; j++) {
            sacc[j] = __builtin_amdgcn_mfma_f32_16x16x32_bf16(kr[j][0], qf[0], zero4, 0, 0, 0);
            sacc[j] = __builtin_amdgcn_mfma_f32_16x16x32_bf16(kr[j][1], qf[1], sacc[j], 0, 0, 0);
        }
        __builtin_amdgcn_s_setprio(0);

        loadK(ktn);   // next K; in flight under taylor + PV

        // ---- taylor weights -> P, packed as 16x16x32 A-fragment ----
        bf16x8 pa8[2];
#pragma unroll
        for (int jj = 0; jj < 2; jj++) {
            ushort_t o[8];
#pragma unroll
            for (int half = 0; half < 2; half++)
#pragma unroll
                for (int r = 0; r < 4; r++) {
                    float s = sacc[2 * jj + half][r];
                    float wgt = fmaf(s, fmaf(s, 0.0078125f, 0.125f), 1.0f);  // 1 + s/8 + s^2/128
                    o[half * 4 + r] = f2bfu(wgt);
                }
            pa8[jj] = *reinterpret_cast<bf16x8*>(o);
        }

        // ---- P @ V' + denominator: 10 intrinsic MFMAs ----
        __builtin_amdgcn_s_setprio(1);
#pragma unroll
        for (int jj = 0; jj < 2; jj++)
#pragma unroll
            for (int dn = 0; dn < 5; dn++)
                oacc[dn] = __builtin_amdgcn_mfma_f32_16x16x32_bf16(pa8[jj], vr[dn][jj], oacc[dn], 0, 0, 0);
        __builtin_amdgcn_s_setprio(0);

        loadV(ktn);   // next V/mask; in flight under next QK + taylor
    }

    // ---- epilogue: denominator broadcast + divide + bf16 write ----
    float inv[4];
#pragma unroll
    for (int r = 0; r < 4; r++) {
        float dn = __shfl(oacc[4][r], lane & 48);   // from lm==0 lane of this quad
        inv[r] = 1.0f / dn;
    }
#pragma unroll
    for (int dn = 0; dn < 4; dn++)
#pragma unroll
        for (int r = 0; r < 4; r++) {
            int qrow = b * 2048 + qt * 64 + wv * 16 + quad * 4 + r;
            attnAb[(size_t)qrow * DIM_ + h * 64 + dn * 16 + lm] = f2bfu(oacc[dn][r] * inv[r]);
        }
}

extern "C" void kernel_launch(void* const* d_in, const int* in_sizes, int n_in,
                              void* d_out, int out_size, void* d_ws, size_t ws_size,
                              hipStream_t stream) {
    (void)in_sizes; (void)n_in; (void)out_size; (void)ws_size;
    const float* x    = (const float*)d_in[0];
    const void*  mask = d_in[1];
    const float* rot  = (const float*)d_in[2];
    const float* Wt   = (const float*)d_in[3];
    const float* Wo   = (const float*)d_in[4];

    char* ws = (char*)d_ws;
    int* wmask       = (int*)(ws + 64);                     // 16 KB
    ushort_t* t      = (ushort_t*)(ws + 32768);             // 12,582,912 B -> 12,615,680
    ushort_t* Xb     = (ushort_t*)(ws + 12615680);          //  4,194,304 B -> 16,809,984
    ushort_t* Wtb    = (ushort_t*)(ws + 16809984);          //  1,572,864 B -> 18,382,848
    ushort_t* Wob    = (ushort_t*)(ws + 18382848);          //    524,288 B -> 18,907,136
    ushort_t* Qb     = (ushort_t*)(ws + 18907136);          //  4,194,304 B -> 23,101,440
    ushort_t* Kb     = (ushort_t*)(ws + 23101440);          //  4,194,304 B -> 27,295,744 (fragment-major)
    ushort_t* VtF    = (ushort_t*)(ws + 27295744);          //  5,242,880 B -> 32,538,624 (fragment-major + den)
    ushort_t* attnAb = (ushort_t*)(ws + 32538624);          //  4,194,304 B -> 36,732,928

    // fused: mask classify+decode + bf16 casts (x, Wt, Wo)
    prep_inputs<<<CASTBLKS_ + 1, 256, 0, stream>>>(x, Wt, Wo, (const unsigned char*)mask,
                                                   Xb, Wtb, Wob, wmask);

    // gemm1: t = x @ Wt^T, bf16 output (TM=64 -> 768 blocks = 3/CU)
    {
        dim3 grid(TOUT_ / 128, ROWS_ / 64);
        mfma_gemm_bt<64, TOUT_, DIM_, true><<<grid, 256, 0, stream>>>(Xb, Wtb, (void*)t);
    }

    // MFMA rotation + q/k bf16 pack (1 wave per position, no LDS)
    rot_qk_mfma<<<ROWS_ / 4, 256, 0, stream>>>(t, rot, wmask, Qb, Kb);

    // masked V fragment-major (+ denominator block)
    {
        dim3 grid(32, 16);
        prep_vt<<<grid, 256, 0, stream>>>(t, wmask, VtF);
    }

    // MFMA flash taylor-attention v10: LDS-free, barrier-free, intrinsic-only
    tmha_attn_mfma<<<512, 256, 0, stream>>>(Qb, Kb, VtF, attnAb);

    // gemm2: out = attn @ Wo^T  (TM=32 -> 512 blocks = 2/CU)
    {
        dim3 grid(DIM_ / 128, ROWS_ / 32);
        mfma_gemm_bt<32, DIM_, DIM_, false><<<grid, 256, 0, stream>>>(attnAb, Wob, d_out);
    }
}

// Round 8
// 192.070 us; speedup vs baseline: 1.0476x; 1.0164x over previous
//
#include <hip/hip_runtime.h>
#include <hip/hip_bf16.h>

// Problem constants
#define B_    2
#define S_    2048
#define DIM_  512
#define H_    8
#define HD_   64
#define TOUT_ 1536   // 2*QK + DIM
#define ROWS_ (B_ * S_)   // 4096

typedef unsigned short ushort_t;
typedef __attribute__((ext_vector_type(8))) __bf16 bf16x8;
typedef __attribute__((ext_vector_type(4))) float floatx4;

#define AS_GLB __attribute__((address_space(1)))
#define AS_LDS __attribute__((address_space(3)))

// ---------- numeric helpers ----------
__device__ __forceinline__ unsigned short f2bfu(float f) {
    unsigned u = __float_as_uint(f);
    unsigned r = (u + 0x7fffu + ((u >> 16) & 1u)) >> 16;
    return (unsigned short)r;
}
__device__ __forceinline__ bf16x8 cvt8(const float* p) {
    float4 a = *reinterpret_cast<const float4*>(p);
    float4 b = *reinterpret_cast<const float4*>(p + 4);
    ushort_t o[8] = {f2bfu(a.x), f2bfu(a.y), f2bfu(a.z), f2bfu(a.w),
                     f2bfu(b.x), f2bfu(b.y), f2bfu(b.z), f2bfu(b.w)};
    return *reinterpret_cast<bf16x8*>(o);
}

// ---------- fused: mask classify+decode (last block) + fp32->bf16 casts ----------
#define XN4_  (ROWS_ * DIM_ / 4)                  // 524288
#define WTN4_ (TOUT_ * DIM_ / 4)                  // 196608
#define WON4_ (DIM_ * DIM_ / 4)                   // 65536
#define CASTBLKS_ ((XN4_ + WTN4_ + WON4_) / 256)  // 3072
__global__ __launch_bounds__(256) void prep_inputs(const float* __restrict__ x,
                                                   const float* __restrict__ wt,
                                                   const float* __restrict__ wo,
                                                   const unsigned char* __restrict__ mb,
                                                   ushort_t* __restrict__ xb,
                                                   ushort_t* __restrict__ wtb,
                                                   ushort_t* __restrict__ wob,
                                                   int* __restrict__ wm) {
    if (blockIdx.x >= CASTBLKS_) {
        __shared__ int s_bf, s_f, s_u8;
        int tid = threadIdx.x;
        if (tid == 0) { s_bf = 0; s_f = 0; s_u8 = 0; }
        __syncthreads();
        int cbf = 0, cf = 0, cu8 = 0;
        for (int i = tid; i < 4096; i += 256) {
            unsigned char v = mb[i];
            if (v == 0x3F || v == 0x80) {
                cf++;
                if ((i & 3) == 1) cbf++;
            } else if (v != 0 && (i & 3) != 0) {
                cu8++;
            }
        }
        atomicAdd(&s_bf, cbf); atomicAdd(&s_f, cf); atomicAdd(&s_u8, cu8);
        __syncthreads();
        int cls = (s_bf > 0) ? 2 : (s_f > 0) ? 3 : (s_u8 > 0) ? 0 : 1;
        for (int i = tid; i < ROWS_; i += 256) {
            int v;
            if (cls == 0)      v = (mb[i] != 0);
            else if (cls == 1) v = (reinterpret_cast<const int*>(mb)[i] != 0);
            else if (cls == 2) v = ((reinterpret_cast<const unsigned short*>(mb)[i] & 0x7fffu) != 0);
            else               v = ((reinterpret_cast<const unsigned int*>(mb)[i] & 0x7fffffffu) != 0);
            wm[i] = v;
        }
        return;
    }
    int i = blockIdx.x * 256 + threadIdx.x;
    const float* s; ushort_t* d; int off;
    if (i < XN4_)              { s = x;  d = xb;  off = i; }
    else if (i < XN4_ + WTN4_) { s = wt; d = wtb; off = i - XN4_; }
    else                       { s = wo; d = wob; off = i - XN4_ - WTN4_; }
    float4 v = reinterpret_cast<const float4*>(s)[off];
    ushort_t o[4] = {f2bfu(v.x), f2bfu(v.y), f2bfu(v.z), f2bfu(v.w)};
    reinterpret_cast<uint2*>(d)[off] = *reinterpret_cast<uint2*>(o);
}

// ==================================================================
// MFMA GEMM (proven R5): C[M,N] = A[M,K] @ B[N,K]^T, XOR-swizzled LDS.
// ==================================================================
template <int TM, int N, int K, bool OUT_BF16>
__global__ __launch_bounds__(256) void mfma_gemm_bt(const ushort_t* __restrict__ A,
                                                    const ushort_t* __restrict__ Bm,
                                                    void* __restrict__ Cout) {
    constexpr int FM = (TM + 31) / 32;
    __shared__ __align__(16) ushort_t As[TM * 64];
    __shared__ __align__(16) ushort_t Bs[128 * 64];
    int tid = threadIdx.x;
    int lane = tid & 63;
    int wv = tid >> 6;
    int wm = wv >> 1, wn = wv & 1;
    int quad = lane >> 4;
    int mrow = lane & 15;
    int bx = blockIdx.x;
    int by = blockIdx.y;

    floatx4 acc[FM][4];
#pragma unroll
    for (int i = 0; i < FM; i++)
#pragma unroll
        for (int j = 0; j < 4; j++) acc[i][j] = (floatx4){0.f, 0.f, 0.f, 0.f};

    for (int k0 = 0; k0 < K; k0 += 64) {
#pragma unroll
        for (int t = 0; t < TM / 32; t++) {
            int p = (wv * (TM / 32) + t) * 64 + lane;
            int row = p >> 3, cp = p & 7;
            int gc = cp ^ (row & 7);
            const ushort_t* ga = A + (size_t)(by * TM + row) * K + k0 + gc * 8;
            __builtin_amdgcn_global_load_lds((const AS_GLB unsigned int*)ga,
                                             (AS_LDS unsigned int*)&As[(size_t)(wv * (TM / 32) + t) * 64 * 8],
                                             16, 0, 0);
        }
#pragma unroll
        for (int t = 0; t < 4; t++) {
            int p = (wv * 4 + t) * 64 + lane;
            int row = p >> 3, cp = p & 7;
            int gc = cp ^ (row & 7);
            const ushort_t* gb = Bm + (size_t)(bx * 128 + row) * K + k0 + gc * 8;
            __builtin_amdgcn_global_load_lds((const AS_GLB unsigned int*)gb,
                                             (AS_LDS unsigned int*)&Bs[(size_t)(wv * 4 + t) * 64 * 8],
                                             16, 0, 0);
        }
        __syncthreads();
#pragma unroll
        for (int ks = 0; ks < 64; ks += 32) {
            int c = (ks >> 3) + quad;
            bf16x8 af[FM], bf[4];
#pragma unroll
            for (int i = 0; i < FM; i++) {
                int row = wm * (TM / 2) + i * 16 + mrow;
                int pos = row * 8 + (c ^ (row & 7));
                af[i] = *reinterpret_cast<const bf16x8*>(&As[pos * 8]);
            }
#pragma unroll
            for (int j = 0; j < 4; j++) {
                int row = wn * 64 + j * 16 + mrow;
                int pos = row * 8 + (c ^ (row & 7));
                bf[j] = *reinterpret_cast<const bf16x8*>(&Bs[pos * 8]);
            }
#pragma unroll
            for (int i = 0; i < FM; i++)
#pragma unroll
                for (int j = 0; j < 4; j++)
                    acc[i][j] = __builtin_amdgcn_mfma_f32_16x16x32_bf16(af[i], bf[j], acc[i][j], 0, 0, 0);
        }
        __syncthreads();
    }

    int col0 = bx * 128 + wn * 64 + mrow;
    int row0 = by * TM + wm * (TM / 2) + quad * 4;
    if constexpr (OUT_BF16) {
        ushort_t* C = reinterpret_cast<ushort_t*>(Cout);
#pragma unroll
        for (int i = 0; i < FM; i++)
#pragma unroll
            for (int j = 0; j < 4; j++)
#pragma unroll
                for (int r = 0; r < 4; r++)
                    C[(size_t)(row0 + i * 16 + r) * N + col0 + j * 16] = f2bfu(acc[i][j][r]);
    } else {
        float* C = reinterpret_cast<float*>(Cout);
#pragma unroll
        for (int i = 0; i < FM; i++)
#pragma unroll
            for (int j = 0; j < 4; j++)
#pragma unroll
                for (int r = 0; r < 4; r++)
                    C[(size_t)(row0 + i * 16 + r) * N + col0 + j * 16] = acc[i][j][r];
    }
}

// ==================================================================
// MFMA rotation (proven R6, bf16 t input): per position s,
// out = in @ R_s^T if mask. One wave per s, no LDS, no barrier.
// K output is FRAGMENT-MAJOR: Kb[bh][kb][c][l][e].
// ==================================================================
__global__ __launch_bounds__(256) void rot_qk_mfma(const ushort_t* __restrict__ t,
                                                   const float* __restrict__ rotG,
                                                   const int* __restrict__ wm,
                                                   ushort_t* __restrict__ Qb,
                                                   ushort_t* __restrict__ Kb) {
    int lane = threadIdx.x & 63;
    int wv = threadIdx.x >> 6;
    int row = blockIdx.x * 4 + wv;     // b*2048 + s
    int b = row >> 11, s = row & 2047;
    int lm = lane & 15, quad = lane >> 4;
    const ushort_t* trow = t + (size_t)row * TOUT_;
    int kb = s >> 4, l = s & 15;

    if (wm[row]) {
        bf16x8 af[2];
#pragma unroll
        for (int kc = 0; kc < 2; kc++)
            af[kc] = *reinterpret_cast<const bf16x8*>(trow + lm * 64 + kc * 32 + quad * 8);

        const float* R = rotG + (size_t)row * 4096;
        floatx4 dacc[4];
#pragma unroll
        for (int nb = 0; nb < 4; nb++) dacc[nb] = (floatx4){0.f, 0.f, 0.f, 0.f};
#pragma unroll
        for (int nb = 0; nb < 4; nb++)
#pragma unroll
            for (int kc = 0; kc < 2; kc++) {
                bf16x8 bfr = cvt8(R + (size_t)(nb * 16 + lm) * 64 + kc * 32 + quad * 8);
                dacc[nb] = __builtin_amdgcn_mfma_f32_16x16x32_bf16(af[kc], bfr, dacc[nb], 0, 0, 0);
            }
#pragma unroll
        for (int nb = 0; nb < 4; nb++)
#pragma unroll
            for (int r = 0; r < 4; r++) {
                int vec = quad * 4 + r;
                int hh = vec & 7;
                ushort_t v = f2bfu(dacc[nb][r]);
                if (vec >= 8) {
                    int c = nb * 2 + (lm >> 3), e = lm & 7;
                    Kb[(((size_t)(b * 8 + hh) * 128 + kb) * 8 + c) * 128 + l * 8 + e] = v;
                } else {
                    Qb[((size_t)(b * 8 + hh) * 2048 + s) * 64 + nb * 16 + lm] = v;
                }
            }
    } else {
#pragma unroll
        for (int nb = 0; nb < 4; nb++)
#pragma unroll
            for (int r = 0; r < 4; r++) {
                int vec = quad * 4 + r;
                int hh = vec & 7;
                ushort_t v = trow[vec * 64 + nb * 16 + lm];
                if (vec >= 8) {
                    int c = nb * 2 + (lm >> 3), e = lm & 7;
                    Kb[(((size_t)(b * 8 + hh) * 128 + kb) * 8 + c) * 128 + l * 8 + e] = v;
                } else {
                    Qb[((size_t)(b * 8 + hh) * 2048 + s) * 64 + nb * 16 + lm] = v;
                }
            }
    }
}

// ==================================================================
// prep: V in PV-B-fragment order (dn=0..3 only) + compact mask
// fragments MfF (replaces the mostly-zero dn=4 denominator block).
// VtF[(((bh*32+st)*4+dn)*2+jj)*4+quad)*16+lm]*8 + e
//   key(jj,quad,e) = jj*32 + (e>>2)*16 + quad*4 + (e&3)
//   value = V[key][d=dn*16+lm] * mask[key]
// MfF[(bh*32+st)*2+jj]*32 + quad*8 + e = mask[key(jj,quad,e)] (bf16 1/0)
// ==================================================================
__global__ __launch_bounds__(256) void prep_vt(const ushort_t* __restrict__ t,
                                               const int* __restrict__ wm,
                                               ushort_t* __restrict__ VtF,
                                               ushort_t* __restrict__ MfF) {
    __shared__ ushort_t tile[64][72];   // [key][dim]
    __shared__ ushort_t umask[64];
    int st = blockIdx.x;   // 0..31 (64-key tile)
    int bh = blockIdx.y;   // 0..15
    int b = bh >> 3, h = bh & 7;
    int tid = threadIdx.x;
    if (tid < 64) umask[tid] = wm[b * 2048 + st * 64 + tid] ? 0xFFFFu : 0u;
#pragma unroll
    for (int i = 0; i < 2; i++) {
        int q = i * 256 + tid;          // 0..511
        int r = q >> 3, c8 = (q & 7) * 8;
        uint4 v = *reinterpret_cast<const uint4*>(
            t + (size_t)(b * 2048 + st * 64 + r) * TOUT_ + 1024 + h * 64 + c8);
        *reinterpret_cast<uint4*>(&tile[r][c8]) = v;
    }
    __syncthreads();
    {   // dn = 0..3 : one thread per (dn, quad, lm); writes jj=0,1
        int dn = tid >> 6, quad = (tid >> 4) & 3, lm = tid & 15;
#pragma unroll
        for (int jj = 0; jj < 2; jj++) {
            ushort_t o[8];
#pragma unroll
            for (int e = 0; e < 8; e++) {
                int key = jj * 32 + ((e >> 2) << 4) + quad * 4 + (e & 3);
                o[e] = (ushort_t)(tile[key][dn * 16 + lm] & umask[key]);
            }
            size_t base = (((((size_t)(bh * 32 + st) * 4 + dn) * 2 + jj) * 4 + quad) * 16 + lm) * 8;
            *reinterpret_cast<uint4*>(VtF + base) = *reinterpret_cast<const uint4*>(o);
        }
    }
    if (tid < 8) {   // mask fragments: 64 bf16 per (bh,st)
        int jj = tid >> 2, quad = tid & 3;
        ushort_t o[8];
#pragma unroll
        for (int e = 0; e < 8; e++) {
            int key = jj * 32 + ((e >> 2) << 4) + quad * 4 + (e & 3);
            o[e] = umask[key] ? (ushort_t)0x3F80u : (ushort_t)0u;
        }
        size_t base = (((size_t)(bh * 32 + st) * 2 + jj) * 4 + quad) * 8;
        *reinterpret_cast<uint4*>(MfF + base) = *reinterpret_cast<const uint4*>(o);
    }
}

// ==================================================================
// MFMA flash taylor-attention v11 = v10 + L2-traffic & latency fixes:
//  - naked s_barrier per tile (NO memory drain): waves of a block stay
//    in lockstep so their identical K/V loads merge in L1/MSHR
//  - depth-2 prefetch: unroll-2 with NAMED A/B register buffers (no
//    runtime indexing -> no scratch); loads for tile t+2 issue at t
//  - denominator V-block (2 KB/tile, mostly zeros) replaced by 128 B
//    broadcast mask fragments + register select (v8's proven trick)
// Zero LDS, intrinsics only. Grid 512 blocks (2/CU), 256 thr.
// ==================================================================
__global__ __launch_bounds__(256) void tmha_attn_mfma(const ushort_t* __restrict__ Qb,
                                                      const ushort_t* __restrict__ KbF,
                                                      const ushort_t* __restrict__ VtF,
                                                      const ushort_t* __restrict__ MfF,
                                                      ushort_t* __restrict__ attnAb) {
    int tid = threadIdx.x;
    int lane = tid & 63;
    int wv = tid >> 6;
    int lm = lane & 15;
    int quad = lane >> 4;

    // XCD-bijective remap (512 = 8 XCDs x 64 contiguous works)
    int bid = blockIdx.x;
    int w = ((bid & 7) << 6) | (bid >> 3);
    int qt = w & 31;        // 0..31
    int bh = w >> 5;        // 0..15
    int b = bh >> 3, h = bh & 7;

    const ushort_t* Kf = KbF + (size_t)bh * 131072;   // [tile][j*8+c][l][e], 4096/tile
    const ushort_t* Vf = VtF + (size_t)bh * 131072;   // [tile][dn][jj][quad][lm][e], 4096/tile
    const ushort_t* Mf = MfF + (size_t)bh * 2048;     // [tile][jj][quad][e], 64/tile

    bf16x8 qf[2];
    {
        const ushort_t* qp = Qb + ((size_t)bh * 2048 + qt * 64 + wv * 16 + lm) * 64 + quad * 8;
        qf[0] = *reinterpret_cast<const bf16x8*>(qp);
        qf[1] = *reinterpret_cast<const bf16x8*>(qp + 32);
    }

    floatx4 zero4 = (floatx4){0.f, 0.f, 0.f, 0.f};
    bf16x8 vzero;
    *reinterpret_cast<uint4*>(&vzero) = (uint4){0u, 0u, 0u, 0u};
    floatx4 oacc[5];
#pragma unroll
    for (int j = 0; j < 5; j++) oacc[j] = zero4;

    bf16x8 kA[4][2], kB[4][2], vA[4][2], vB[4][2], mA[2], mB[2];

    auto loadK = [&](bf16x8 (&kr)[4][2], int tt) {
        const ushort_t* p = Kf + (size_t)(tt & 31) * 4096 + quad * 128 + lm * 8;
#pragma unroll
        for (int j = 0; j < 4; j++)
#pragma unroll
            for (int kc = 0; kc < 2; kc++)
                kr[j][kc] = *reinterpret_cast<const bf16x8*>(p + (j * 8 + kc * 4) * 128);
    };
    auto loadV = [&](bf16x8 (&vr)[4][2], int tt) {
        const ushort_t* p = Vf + (size_t)(tt & 31) * 4096 + quad * 128 + lm * 8;
#pragma unroll
        for (int dn = 0; dn < 4; dn++)
#pragma unroll
            for (int jj = 0; jj < 2; jj++)
                vr[dn][jj] = *reinterpret_cast<const bf16x8*>(p + dn * 1024 + jj * 512);
    };
    auto loadM = [&](bf16x8 (&mf)[2], int tt) {
        const ushort_t* p = Mf + (size_t)(tt & 31) * 64 + quad * 8;
        mf[0] = *reinterpret_cast<const bf16x8*>(p);
        mf[1] = *reinterpret_cast<const bf16x8*>(p + 32);
    };

    auto step = [&](bf16x8 (&kr)[4][2], bf16x8 (&vr)[4][2], bf16x8 (&mf)[2],
                    bf16x8 (&krN)[4][2], bf16x8 (&vrN)[4][2], bf16x8 (&mfN)[2], int tpre) {
        __builtin_amdgcn_s_barrier();   // lockstep only: no memory semantics

        // ---- swapped QK^T: sacc[j][r] = S[key=j*16+quad*4+r][q=lm] ----
        floatx4 sacc[4];
        __builtin_amdgcn_s_setprio(1);
#pragma unroll
        for (int j = 0; j < 4; j++) {
            sacc[j] = __builtin_amdgcn_mfma_f32_16x16x32_bf16(kr[j][0], qf[0], zero4, 0, 0, 0);
            sacc[j] = __builtin_amdgcn_mfma_f32_16x16x32_bf16(kr[j][1], qf[1], sacc[j], 0, 0, 0);
        }
        __builtin_amdgcn_s_setprio(0);

        loadK(krN, tpre);   // tile t+2 K; in flight across the next tile

        // ---- taylor weights -> P, packed as 16x16x32 A-fragment ----
        bf16x8 pa8[2];
#pragma unroll
        for (int jj = 0; jj < 2; jj++) {
            ushort_t o[8];
#pragma unroll
            for (int half = 0; half < 2; half++)
#pragma unroll
                for (int r = 0; r < 4; r++) {
                    float s = sacc[2 * jj + half][r];
                    float wgt = fmaf(s, fmaf(s, 0.0078125f, 0.125f), 1.0f);  // 1 + s/8 + s^2/128
                    o[half * 4 + r] = f2bfu(wgt);
                }
            pa8[jj] = *reinterpret_cast<bf16x8*>(o);
        }

        // ---- P @ V' + denominator (mask fragment, register select) ----
        __builtin_amdgcn_s_setprio(1);
#pragma unroll
        for (int jj = 0; jj < 2; jj++) {
#pragma unroll
            for (int dn = 0; dn < 4; dn++)
                oacc[dn] = __builtin_amdgcn_mfma_f32_16x16x32_bf16(pa8[jj], vr[dn][jj], oacc[dn], 0, 0, 0);
            bf16x8 vb = (lm == 0) ? mf[jj] : vzero;   // denom col 0 carries mask
            oacc[4] = __builtin_amdgcn_mfma_f32_16x16x32_bf16(pa8[jj], vb, oacc[4], 0, 0, 0);
        }
        __builtin_amdgcn_s_setprio(0);

        loadV(vrN, tpre); loadM(mfN, tpre);   // tile t+2 V/mask
    };

    loadK(kA, 0); loadV(vA, 0); loadM(mA, 0);
    loadK(kB, 1); loadV(vB, 1); loadM(mB, 1);
#pragma unroll 1
    for (int it = 0; it < 16; it++) {
        step(kA, vA, mA, kA, vA, mA, 2 * it + 2);
        step(kB, vB, mB, kB, vB, mB, 2 * it + 3);
    }

    // ---- epilogue: denominator broadcast + divide + bf16 write ----
    float inv[4];
#pragma unroll
    for (int r = 0; r < 4; r++) {
        float dn = __shfl(oacc[4][r], lane & 48);   // from lm==0 lane of this quad
        inv[r] = 1.0f / dn;
    }
#pragma unroll
    for (int dn = 0; dn < 4; dn++)
#pragma unroll
        for (int r = 0; r < 4; r++) {
            int qrow = b * 2048 + qt * 64 + wv * 16 + quad * 4 + r;
            attnAb[(size_t)qrow * DIM_ + h * 64 + dn * 16 + lm] = f2bfu(oacc[dn][r] * inv[r]);
        }
}

extern "C" void kernel_launch(void* const* d_in, const int* in_sizes, int n_in,
                              void* d_out, int out_size, void* d_ws, size_t ws_size,
                              hipStream_t stream) {
    (void)in_sizes; (void)n_in; (void)out_size; (void)ws_size;
    const float* x    = (const float*)d_in[0];
    const void*  mask = d_in[1];
    const float* rot  = (const float*)d_in[2];
    const float* Wt   = (const float*)d_in[3];
    const float* Wo   = (const float*)d_in[4];

    char* ws = (char*)d_ws;
    int* wmask       = (int*)(ws + 64);                     // 16 KB
    ushort_t* t      = (ushort_t*)(ws + 32768);             // 12,582,912 B -> 12,615,680
    ushort_t* Xb     = (ushort_t*)(ws + 12615680);          //  4,194,304 B -> 16,809,984
    ushort_t* Wtb    = (ushort_t*)(ws + 16809984);          //  1,572,864 B -> 18,382,848
    ushort_t* Wob    = (ushort_t*)(ws + 18382848);          //    524,288 B -> 18,907,136
    ushort_t* Qb     = (ushort_t*)(ws + 18907136);          //  4,194,304 B -> 23,101,440
    ushort_t* Kb     = (ushort_t*)(ws + 23101440);          //  4,194,304 B -> 27,295,744 (fragment-major)
    ushort_t* VtF    = (ushort_t*)(ws + 27295744);          //  4,194,304 B -> 31,490,048 (fragment-major)
    ushort_t* MfF    = (ushort_t*)(ws + 31490048);          //     65,536 B -> 31,555,584 (mask fragments)
    ushort_t* attnAb = (ushort_t*)(ws + 31555584);          //  4,194,304 B -> 35,749,888

    // fused: mask classify+decode + bf16 casts (x, Wt, Wo)
    prep_inputs<<<CASTBLKS_ + 1, 256, 0, stream>>>(x, Wt, Wo, (const unsigned char*)mask,
                                                   Xb, Wtb, Wob, wmask);

    // gemm1: t = x @ Wt^T, bf16 output (TM=64 -> 768 blocks = 3/CU)
    {
        dim3 grid(TOUT_ / 128, ROWS_ / 64);
        mfma_gemm_bt<64, TOUT_, DIM_, true><<<grid, 256, 0, stream>>>(Xb, Wtb, (void*)t);
    }

    // MFMA rotation + q/k bf16 pack (1 wave per position, no LDS)
    rot_qk_mfma<<<ROWS_ / 4, 256, 0, stream>>>(t, rot, wmask, Qb, Kb);

    // masked V fragment-major + mask fragments
    {
        dim3 grid(32, 16);
        prep_vt<<<grid, 256, 0, stream>>>(t, wmask, VtF, MfF);
    }

    // MFMA flash taylor-attention v11: lockstep + depth-2 prefetch
    tmha_attn_mfma<<<512, 256, 0, stream>>>(Qb, Kb, VtF, MfF, attnAb);

    // gemm2: out = attn @ Wo^T  (TM=32 -> 512 blocks = 2/CU)
    {
        dim3 grid(DIM_ / 128, ROWS_ / 32);
        mfma_gemm_bt<32, DIM_, DIM_, false><<<grid, 256, 0, stream>>>(attnAb, Wob, d_out);
    }
}

// Round 9
// 189.416 us; speedup vs baseline: 1.0622x; 1.0140x over previous
//
#include <hip/hip_runtime.h>
#include <hip/hip_bf16.h>

// Problem constants
#define B_    2
#define S_    2048
#define DIM_  512
#define H_    8
#define HD_   64
#define TOUT_ 1536   // 2*QK + DIM
#define ROWS_ (B_ * S_)   // 4096

typedef unsigned short ushort_t;
typedef __attribute__((ext_vector_type(8))) __bf16 bf16x8;
typedef __attribute__((ext_vector_type(4))) float floatx4;

#define AS_GLB __attribute__((address_space(1)))
#define AS_LDS __attribute__((address_space(3)))

// ---------- numeric helpers ----------
__device__ __forceinline__ unsigned short f2bfu(float f) {
    unsigned u = __float_as_uint(f);
    unsigned r = (u + 0x7fffu + ((u >> 16) & 1u)) >> 16;
    return (unsigned short)r;
}
__device__ __forceinline__ bf16x8 cvt8(const float* p) {
    float4 a = *reinterpret_cast<const float4*>(p);
    float4 b = *reinterpret_cast<const float4*>(p + 4);
    ushort_t o[8] = {f2bfu(a.x), f2bfu(a.y), f2bfu(a.z), f2bfu(a.w),
                     f2bfu(b.x), f2bfu(b.y), f2bfu(b.z), f2bfu(b.w)};
    return *reinterpret_cast<bf16x8*>(o);
}

// ---------- fused: mask classify+decode (last block) + fp32->bf16 casts ----------
#define XN4_  (ROWS_ * DIM_ / 4)                  // 524288
#define WTN4_ (TOUT_ * DIM_ / 4)                  // 196608
#define WON4_ (DIM_ * DIM_ / 4)                   // 65536
#define CASTBLKS_ ((XN4_ + WTN4_ + WON4_) / 256)  // 3072
__global__ __launch_bounds__(256) void prep_inputs(const float* __restrict__ x,
                                                   const float* __restrict__ wt,
                                                   const float* __restrict__ wo,
                                                   const unsigned char* __restrict__ mb,
                                                   ushort_t* __restrict__ xb,
                                                   ushort_t* __restrict__ wtb,
                                                   ushort_t* __restrict__ wob,
                                                   int* __restrict__ wm) {
    if (blockIdx.x >= CASTBLKS_) {
        __shared__ int s_bf, s_f, s_u8;
        int tid = threadIdx.x;
        if (tid == 0) { s_bf = 0; s_f = 0; s_u8 = 0; }
        __syncthreads();
        int cbf = 0, cf = 0, cu8 = 0;
        for (int i = tid; i < 4096; i += 256) {
            unsigned char v = mb[i];
            if (v == 0x3F || v == 0x80) {
                cf++;
                if ((i & 3) == 1) cbf++;
            } else if (v != 0 && (i & 3) != 0) {
                cu8++;
            }
        }
        atomicAdd(&s_bf, cbf); atomicAdd(&s_f, cf); atomicAdd(&s_u8, cu8);
        __syncthreads();
        int cls = (s_bf > 0) ? 2 : (s_f > 0) ? 3 : (s_u8 > 0) ? 0 : 1;
        for (int i = tid; i < ROWS_; i += 256) {
            int v;
            if (cls == 0)      v = (mb[i] != 0);
            else if (cls == 1) v = (reinterpret_cast<const int*>(mb)[i] != 0);
            else if (cls == 2) v = ((reinterpret_cast<const unsigned short*>(mb)[i] & 0x7fffu) != 0);
            else               v = ((reinterpret_cast<const unsigned int*>(mb)[i] & 0x7fffffffu) != 0);
            wm[i] = v;
        }
        return;
    }
    int i = blockIdx.x * 256 + threadIdx.x;
    const float* s; ushort_t* d; int off;
    if (i < XN4_)              { s = x;  d = xb;  off = i; }
    else if (i < XN4_ + WTN4_) { s = wt; d = wtb; off = i - XN4_; }
    else                       { s = wo; d = wob; off = i - XN4_ - WTN4_; }
    float4 v = reinterpret_cast<const float4*>(s)[off];
    ushort_t o[4] = {f2bfu(v.x), f2bfu(v.y), f2bfu(v.z), f2bfu(v.w)};
    reinterpret_cast<uint2*>(d)[off] = *reinterpret_cast<uint2*>(o);
}

// ==================================================================
// MFMA GEMM (proven R5): C[M,N] = A[M,K] @ B[N,K]^T, XOR-swizzled LDS.
// ==================================================================
template <int TM, int N, int K, bool OUT_BF16>
__global__ __launch_bounds__(256) void mfma_gemm_bt(const ushort_t* __restrict__ A,
                                                    const ushort_t* __restrict__ Bm,
                                                    void* __restrict__ Cout) {
    constexpr int FM = (TM + 31) / 32;
    __shared__ __align__(16) ushort_t As[TM * 64];
    __shared__ __align__(16) ushort_t Bs[128 * 64];
    int tid = threadIdx.x;
    int lane = tid & 63;
    int wv = tid >> 6;
    int wm = wv >> 1, wn = wv & 1;
    int quad = lane >> 4;
    int mrow = lane & 15;
    int bx = blockIdx.x;
    int by = blockIdx.y;

    floatx4 acc[FM][4];
#pragma unroll
    for (int i = 0; i < FM; i++)
#pragma unroll
        for (int j = 0; j < 4; j++) acc[i][j] = (floatx4){0.f, 0.f, 0.f, 0.f};

    for (int k0 = 0; k0 < K; k0 += 64) {
#pragma unroll
        for (int t = 0; t < TM / 32; t++) {
            int p = (wv * (TM / 32) + t) * 64 + lane;
            int row = p >> 3, cp = p & 7;
            int gc = cp ^ (row & 7);
            const ushort_t* ga = A + (size_t)(by * TM + row) * K + k0 + gc * 8;
            __builtin_amdgcn_global_load_lds((const AS_GLB unsigned int*)ga,
                                             (AS_LDS unsigned int*)&As[(size_t)(wv * (TM / 32) + t) * 64 * 8],
                                             16, 0, 0);
        }
#pragma unroll
        for (int t = 0; t < 4; t++) {
            int p = (wv * 4 + t) * 64 + lane;
            int row = p >> 3, cp = p & 7;
            int gc = cp ^ (row & 7);
            const ushort_t* gb = Bm + (size_t)(bx * 128 + row) * K + k0 + gc * 8;
            __builtin_amdgcn_global_load_lds((const AS_GLB unsigned int*)gb,
                                             (AS_LDS unsigned int*)&Bs[(size_t)(wv * 4 + t) * 64 * 8],
                                             16, 0, 0);
        }
        __syncthreads();
#pragma unroll
        for (int ks = 0; ks < 64; ks += 32) {
            int c = (ks >> 3) + quad;
            bf16x8 af[FM], bf[4];
#pragma unroll
            for (int i = 0; i < FM; i++) {
                int row = wm * (TM / 2) + i * 16 + mrow;
                int pos = row * 8 + (c ^ (row & 7));
                af[i] = *reinterpret_cast<const bf16x8*>(&As[pos * 8]);
            }
#pragma unroll
            for (int j = 0; j < 4; j++) {
                int row = wn * 64 + j * 16 + mrow;
                int pos = row * 8 + (c ^ (row & 7));
                bf[j] = *reinterpret_cast<const bf16x8*>(&Bs[pos * 8]);
            }
#pragma unroll
            for (int i = 0; i < FM; i++)
#pragma unroll
                for (int j = 0; j < 4; j++)
                    acc[i][j] = __builtin_amdgcn_mfma_f32_16x16x32_bf16(af[i], bf[j], acc[i][j], 0, 0, 0);
        }
        __syncthreads();
    }

    int col0 = bx * 128 + wn * 64 + mrow;
    int row0 = by * TM + wm * (TM / 2) + quad * 4;
    if constexpr (OUT_BF16) {
        ushort_t* C = reinterpret_cast<ushort_t*>(Cout);
#pragma unroll
        for (int i = 0; i < FM; i++)
#pragma unroll
            for (int j = 0; j < 4; j++)
#pragma unroll
                for (int r = 0; r < 4; r++)
                    C[(size_t)(row0 + i * 16 + r) * N + col0 + j * 16] = f2bfu(acc[i][j][r]);
    } else {
        float* C = reinterpret_cast<float*>(Cout);
#pragma unroll
        for (int i = 0; i < FM; i++)
#pragma unroll
            for (int j = 0; j < 4; j++)
#pragma unroll
                for (int r = 0; r < 4; r++)
                    C[(size_t)(row0 + i * 16 + r) * N + col0 + j * 16] = acc[i][j][r];
    }
}

// ==================================================================
// MFMA rotation (proven R6, bf16 t input): per position s,
// out = in @ R_s^T if mask. One wave per s, no LDS, no barrier.
// K output is FRAGMENT-MAJOR: Kb[bh][kb][c][l][e].
// ==================================================================
__global__ __launch_bounds__(256) void rot_qk_mfma(const ushort_t* __restrict__ t,
                                                   const float* __restrict__ rotG,
                                                   const int* __restrict__ wm,
                                                   ushort_t* __restrict__ Qb,
                                                   ushort_t* __restrict__ Kb) {
    int lane = threadIdx.x & 63;
    int wv = threadIdx.x >> 6;
    int row = blockIdx.x * 4 + wv;     // b*2048 + s
    int b = row >> 11, s = row & 2047;
    int lm = lane & 15, quad = lane >> 4;
    const ushort_t* trow = t + (size_t)row * TOUT_;
    int kb = s >> 4, l = s & 15;

    if (wm[row]) {
        bf16x8 af[2];
#pragma unroll
        for (int kc = 0; kc < 2; kc++)
            af[kc] = *reinterpret_cast<const bf16x8*>(trow + lm * 64 + kc * 32 + quad * 8);

        const float* R = rotG + (size_t)row * 4096;
        floatx4 dacc[4];
#pragma unroll
        for (int nb = 0; nb < 4; nb++) dacc[nb] = (floatx4){0.f, 0.f, 0.f, 0.f};
#pragma unroll
        for (int nb = 0; nb < 4; nb++)
#pragma unroll
            for (int kc = 0; kc < 2; kc++) {
                bf16x8 bfr = cvt8(R + (size_t)(nb * 16 + lm) * 64 + kc * 32 + quad * 8);
                dacc[nb] = __builtin_amdgcn_mfma_f32_16x16x32_bf16(af[kc], bfr, dacc[nb], 0, 0, 0);
            }
#pragma unroll
        for (int nb = 0; nb < 4; nb++)
#pragma unroll
            for (int r = 0; r < 4; r++) {
                int vec = quad * 4 + r;
                int hh = vec & 7;
                ushort_t v = f2bfu(dacc[nb][r]);
                if (vec >= 8) {
                    int c = nb * 2 + (lm >> 3), e = lm & 7;
                    Kb[(((size_t)(b * 8 + hh) * 128 + kb) * 8 + c) * 128 + l * 8 + e] = v;
                } else {
                    Qb[((size_t)(b * 8 + hh) * 2048 + s) * 64 + nb * 16 + lm] = v;
                }
            }
    } else {
#pragma unroll
        for (int nb = 0; nb < 4; nb++)
#pragma unroll
            for (int r = 0; r < 4; r++) {
                int vec = quad * 4 + r;
                int hh = vec & 7;
                ushort_t v = trow[vec * 64 + nb * 16 + lm];
                if (vec >= 8) {
                    int c = nb * 2 + (lm >> 3), e = lm & 7;
                    Kb[(((size_t)(b * 8 + hh) * 128 + kb) * 8 + c) * 128 + l * 8 + e] = v;
                } else {
                    Qb[((size_t)(b * 8 + hh) * 2048 + s) * 64 + nb * 16 + lm] = v;
                }
            }
    }
}

// ==================================================================
// prep: V in PV-B-fragment order (dn=0..3) + compact mask fragments.
// VtF[(((bh*32+st)*4+dn)*2+jj)*4+quad)*16+lm]*8 + e
//   key(jj,quad,e) = jj*32 + (e>>2)*16 + quad*4 + (e&3)
//   value = V[key][d=dn*16+lm] * mask[key]
// MfF[(bh*32+st)*2+jj]*32 + quad*8 + e = mask[key(jj,quad,e)] (bf16 1/0)
// ==================================================================
__global__ __launch_bounds__(256) void prep_vt(const ushort_t* __restrict__ t,
                                               const int* __restrict__ wm,
                                               ushort_t* __restrict__ VtF,
                                               ushort_t* __restrict__ MfF) {
    __shared__ ushort_t tile[64][72];   // [key][dim]
    __shared__ ushort_t umask[64];
    int st = blockIdx.x;   // 0..31 (64-key tile)
    int bh = blockIdx.y;   // 0..15
    int b = bh >> 3, h = bh & 7;
    int tid = threadIdx.x;
    if (tid < 64) umask[tid] = wm[b * 2048 + st * 64 + tid] ? 0xFFFFu : 0u;
#pragma unroll
    for (int i = 0; i < 2; i++) {
        int q = i * 256 + tid;          // 0..511
        int r = q >> 3, c8 = (q & 7) * 8;
        uint4 v = *reinterpret_cast<const uint4*>(
            t + (size_t)(b * 2048 + st * 64 + r) * TOUT_ + 1024 + h * 64 + c8);
        *reinterpret_cast<uint4*>(&tile[r][c8]) = v;
    }
    __syncthreads();
    {   // dn = 0..3 : one thread per (dn, quad, lm); writes jj=0,1
        int dn = tid >> 6, quad = (tid >> 4) & 3, lm = tid & 15;
#pragma unroll
        for (int jj = 0; jj < 2; jj++) {
            ushort_t o[8];
#pragma unroll
            for (int e = 0; e < 8; e++) {
                int key = jj * 32 + ((e >> 2) << 4) + quad * 4 + (e & 3);
                o[e] = (ushort_t)(tile[key][dn * 16 + lm] & umask[key]);
            }
            size_t base = (((((size_t)(bh * 32 + st) * 4 + dn) * 2 + jj) * 4 + quad) * 16 + lm) * 8;
            *reinterpret_cast<uint4*>(VtF + base) = *reinterpret_cast<const uint4*>(o);
        }
    }
    if (tid < 8) {   // mask fragments: 64 bf16 per (bh,st)
        int jj = tid >> 2, quad = tid & 3;
        ushort_t o[8];
#pragma unroll
        for (int e = 0; e < 8; e++) {
            int key = jj * 32 + ((e >> 2) << 4) + quad * 4 + (e & 3);
            o[e] = umask[key] ? (ushort_t)0x3F80u : (ushort_t)0u;
        }
        size_t base = (((size_t)(bh * 32 + st) * 2 + jj) * 4 + quad) * 8;
        *reinterpret_cast<uint4*>(MfF + base) = *reinterpret_cast<const uint4*>(o);
    }
}

// ==================================================================
// MFMA flash taylor-attention v12 = v11 + K/V amortization (the L1
// bytes/work fix):
//  - each wave owns 32 q-rows (2 groups of 16): same 18 KB K/V per
//    wave-tile feeds 2x the MFMA work -> per-CU vector-memory demand
//    halves (was ~39 B/cyc/CU, at the L1 service ceiling)
//  - ksplit=2 restores 512 blocks (2/CU, 8 waves/CU); fp32 numer/den
//    epilogue + proven standalone combine kernel
//  - otherwise v11: LDS-free, intrinsic-only, register prefetch (WAR),
//    naked s_barrier lockstep, XCD-bijective remap
// __launch_bounds__(256,2) caps VGPR at 256 (2 waves/SIMD guaranteed).
// ==================================================================
__global__ __launch_bounds__(256, 2) void tmha_attn_mfma(const ushort_t* __restrict__ Qb,
                                                         const ushort_t* __restrict__ KbF,
                                                         const ushort_t* __restrict__ VtF,
                                                         const ushort_t* __restrict__ MfF,
                                                         float* __restrict__ numer,
                                                         float* __restrict__ den) {
    int tid = threadIdx.x;
    int lane = tid & 63;
    int wv = tid >> 6;
    int lm = lane & 15;
    int quad = lane >> 4;

    // XCD-bijective remap (512 = 8 XCDs x 64 contiguous works -> 2 bh/XCD)
    int bid = blockIdx.x;
    int w = ((bid & 7) << 6) | (bid >> 3);
    int ks = w & 1;         // key split
    int qt = (w >> 1) & 15; // 0..15 (128 q per block)
    int bh = w >> 5;        // 0..15
    int b = bh >> 3, h = bh & 7;

    const ushort_t* Kf = KbF + (size_t)bh * 131072;   // [tile][j*8+c][l][e], 4096/tile
    const ushort_t* Vf = VtF + (size_t)bh * 131072;   // [tile][dn][jj][quad][lm][e], 4096/tile
    const ushort_t* Mf = MfF + (size_t)bh * 2048;     // [tile][jj][quad][e], 64/tile

    bf16x8 qf[2][2];
#pragma unroll
    for (int g = 0; g < 2; g++) {
        const ushort_t* qp = Qb + ((size_t)bh * 2048 + qt * 128 + wv * 32 + g * 16 + lm) * 64 + quad * 8;
        qf[g][0] = *reinterpret_cast<const bf16x8*>(qp);
        qf[g][1] = *reinterpret_cast<const bf16x8*>(qp + 32);
    }

    floatx4 zero4 = (floatx4){0.f, 0.f, 0.f, 0.f};
    bf16x8 vzero;
    *reinterpret_cast<uint4*>(&vzero) = (uint4){0u, 0u, 0u, 0u};
    floatx4 oacc[2][5];
#pragma unroll
    for (int g = 0; g < 2; g++)
#pragma unroll
        for (int j = 0; j < 5; j++) oacc[g][j] = zero4;

    bf16x8 kr[4][2], vr[4][2], mf[2];
    auto loadK = [&](int tile) {
        const ushort_t* p = Kf + (size_t)tile * 4096 + quad * 128 + lm * 8;
#pragma unroll
        for (int j = 0; j < 4; j++)
#pragma unroll
            for (int kc = 0; kc < 2; kc++)
                kr[j][kc] = *reinterpret_cast<const bf16x8*>(p + (j * 8 + kc * 4) * 128);
    };
    auto loadV = [&](int tile) {
        const ushort_t* p = Vf + (size_t)tile * 4096 + quad * 128 + lm * 8;
#pragma unroll
        for (int dn = 0; dn < 4; dn++)
#pragma unroll
            for (int jj = 0; jj < 2; jj++)
                vr[dn][jj] = *reinterpret_cast<const bf16x8*>(p + dn * 1024 + jj * 512);
    };
    auto loadM = [&](int tile) {
        const ushort_t* p = Mf + (size_t)tile * 64 + quad * 8;
        mf[0] = *reinterpret_cast<const bf16x8*>(p);
        mf[1] = *reinterpret_cast<const bf16x8*>(p + 32);
    };

    int t0 = ks * 16;
    loadK(t0); loadV(t0); loadM(t0);
#pragma unroll 1
    for (int tt = 0; tt < 16; tt++) {
        int tn = (tt == 15) ? t0 : t0 + tt + 1;   // wrapped prefetch addr (values unused on last)
        __builtin_amdgcn_s_barrier();             // lockstep only: no memory semantics

        // ---- swapped QK^T, both q-groups: sacc[g][j][r] = S[key][q=lm] ----
        floatx4 sacc[2][4];
        __builtin_amdgcn_s_setprio(1);
#pragma unroll
        for (int g = 0; g < 2; g++)
#pragma unroll
            for (int j = 0; j < 4; j++) {
                sacc[g][j] = __builtin_amdgcn_mfma_f32_16x16x32_bf16(kr[j][0], qf[g][0], zero4, 0, 0, 0);
                sacc[g][j] = __builtin_amdgcn_mfma_f32_16x16x32_bf16(kr[j][1], qf[g][1], sacc[g][j], 0, 0, 0);
            }
        __builtin_amdgcn_s_setprio(0);

        loadK(tn);   // next K; WAR on kr, in flight under taylor + PV

        // ---- taylor weights -> P, packed as 16x16x32 A-fragment ----
        bf16x8 pa8[2][2];
#pragma unroll
        for (int g = 0; g < 2; g++)
#pragma unroll
            for (int jj = 0; jj < 2; jj++) {
                ushort_t o[8];
#pragma unroll
                for (int half = 0; half < 2; half++)
#pragma unroll
                    for (int r = 0; r < 4; r++) {
                        float s = sacc[g][2 * jj + half][r];
                        float wgt = fmaf(s, fmaf(s, 0.0078125f, 0.125f), 1.0f);  // 1 + s/8 + s^2/128
                        o[half * 4 + r] = f2bfu(wgt);
                    }
                pa8[g][jj] = *reinterpret_cast<bf16x8*>(o);
            }

        // ---- P @ V' + denominator (mask fragment, register select) ----
        __builtin_amdgcn_s_setprio(1);
#pragma unroll
        for (int g = 0; g < 2; g++)
#pragma unroll
            for (int jj = 0; jj < 2; jj++) {
#pragma unroll
                for (int dn = 0; dn < 4; dn++)
                    oacc[g][dn] = __builtin_amdgcn_mfma_f32_16x16x32_bf16(pa8[g][jj], vr[dn][jj], oacc[g][dn], 0, 0, 0);
                bf16x8 vb = (lm == 0) ? mf[jj] : vzero;   // denom col 0 carries mask
                oacc[g][4] = __builtin_amdgcn_mfma_f32_16x16x32_bf16(pa8[g][jj], vb, oacc[g][4], 0, 0, 0);
            }
        __builtin_amdgcn_s_setprio(0);

        loadV(tn); loadM(tn);   // next V/mask; WAR, in flight under next QK
    }

    // ---- epilogue: write split numerator + denominator (fp32) ----
#pragma unroll
    for (int g = 0; g < 2; g++) {
#pragma unroll
        for (int dn = 0; dn < 4; dn++)
#pragma unroll
            for (int r = 0; r < 4; r++) {
                int qrow = b * 2048 + qt * 128 + wv * 32 + g * 16 + quad * 4 + r;
                numer[((size_t)ks * ROWS_ + qrow) * DIM_ + h * 64 + dn * 16 + lm] = oacc[g][dn][r];
            }
        if (lm == 0) {
#pragma unroll
            for (int r = 0; r < 4; r++) {
                int qrow = b * 2048 + qt * 128 + wv * 32 + g * 16 + quad * 4 + r;
                den[((size_t)ks * ROWS_ + qrow) * 8 + h] = oacc[g][4][r];
            }
        }
    }
}

// ---------- combine splits: attn = (n0+n1)/(d0+d1), bf16 (proven R1) ----------
__global__ __launch_bounds__(256) void attn_combine(const float* __restrict__ numer,
                                                    const float* __restrict__ den,
                                                    ushort_t* __restrict__ attnAb) {
    int i = blockIdx.x * 256 + threadIdx.x;      // over 4096*128 float4s
    int row = i >> 7;
    int c4 = (i & 127) * 4;
    int h = c4 >> 6;
    float4 n0 = *reinterpret_cast<const float4*>(&numer[(size_t)row * DIM_ + c4]);
    float4 n1 = *reinterpret_cast<const float4*>(&numer[((size_t)ROWS_ + row) * DIM_ + c4]);
    float d = den[(size_t)row * 8 + h] + den[((size_t)ROWS_ + row) * 8 + h];
    float inv = 1.0f / d;
    ushort_t o[4] = {f2bfu((n0.x + n1.x) * inv), f2bfu((n0.y + n1.y) * inv),
                     f2bfu((n0.z + n1.z) * inv), f2bfu((n0.w + n1.w) * inv)};
    *reinterpret_cast<uint2*>(&attnAb[(size_t)row * DIM_ + c4]) = *reinterpret_cast<uint2*>(o);
}

extern "C" void kernel_launch(void* const* d_in, const int* in_sizes, int n_in,
                              void* d_out, int out_size, void* d_ws, size_t ws_size,
                              hipStream_t stream) {
    (void)in_sizes; (void)n_in; (void)out_size; (void)ws_size;
    const float* x    = (const float*)d_in[0];
    const void*  mask = d_in[1];
    const float* rot  = (const float*)d_in[2];
    const float* Wt   = (const float*)d_in[3];
    const float* Wo   = (const float*)d_in[4];

    char* ws = (char*)d_ws;
    int* wmask       = (int*)(ws + 64);                     // 16 KB
    ushort_t* t      = (ushort_t*)(ws + 32768);             // 12,582,912 B -> 12,615,680
    ushort_t* Xb     = (ushort_t*)(ws + 12615680);          //  4,194,304 B -> 16,809,984
    ushort_t* Wtb    = (ushort_t*)(ws + 16809984);          //  1,572,864 B -> 18,382,848
    ushort_t* Wob    = (ushort_t*)(ws + 18382848);          //    524,288 B -> 18,907,136
    ushort_t* Qb     = (ushort_t*)(ws + 18907136);          //  4,194,304 B -> 23,101,440
    ushort_t* Kb     = (ushort_t*)(ws + 23101440);          //  4,194,304 B -> 27,295,744 (fragment-major)
    ushort_t* VtF    = (ushort_t*)(ws + 27295744);          //  4,194,304 B -> 31,490,048 (fragment-major)
    ushort_t* MfF    = (ushort_t*)(ws + 31490048);          //     65,536 B -> 31,555,584 (mask fragments)
    ushort_t* attnAb = (ushort_t*)(ws + 31555584);          //  4,194,304 B -> 35,749,888
    // split-K outputs alias dead regions: t+Xb (both dead after prep_vt/gemm1)
    float* numer     = (float*)(ws + 32768);                // 16,777,216 B (== t+Xb exactly)
    float* den       = (float*)(ws + 16809984);             //    262,144 B (aliases dead Wtb)

    // fused: mask classify+decode + bf16 casts (x, Wt, Wo)
    prep_inputs<<<CASTBLKS_ + 1, 256, 0, stream>>>(x, Wt, Wo, (const unsigned char*)mask,
                                                   Xb, Wtb, Wob, wmask);

    // gemm1: t = x @ Wt^T, bf16 output (TM=64 -> 768 blocks = 3/CU)
    {
        dim3 grid(TOUT_ / 128, ROWS_ / 64);
        mfma_gemm_bt<64, TOUT_, DIM_, true><<<grid, 256, 0, stream>>>(Xb, Wtb, (void*)t);
    }

    // MFMA rotation + q/k bf16 pack (1 wave per position, no LDS)
    rot_qk_mfma<<<ROWS_ / 4, 256, 0, stream>>>(t, rot, wmask, Qb, Kb);

    // masked V fragment-major + mask fragments
    {
        dim3 grid(32, 16);
        prep_vt<<<grid, 256, 0, stream>>>(t, wmask, VtF, MfF);
    }

    // MFMA flash taylor-attention v12: 32 q/wave + ksplit=2
    tmha_attn_mfma<<<512, 256, 0, stream>>>(Qb, Kb, VtF, MfF, numer, den);
    attn_combine<<<(ROWS_ * 128) / 256, 256, 0, stream>>>(numer, den, attnAb);

    // gemm2: out = attn @ Wo^T  (TM=32 -> 512 blocks = 2/CU)
    {
        dim3 grid(DIM_ / 128, ROWS_ / 32);
        mfma_gemm_bt<32, DIM_, DIM_, false><<<grid, 256, 0, stream>>>(attnAb, Wob, d_out);
    }
}